// Round 1
// 1644.667 us; speedup vs baseline: 1.1302x; 1.1302x over previous
//
#include <hip/hip_runtime.h>
#include <hip/hip_bf16.h>

// ---------------- problem constants ----------------
#define S_TOKENS 16384   // B*N
#define DMODEL   1024
#define NEXP     8
#define HFF      4096
#define CAP      2560    // int(S*1.25/E)
#define OUT_TOTAL (S_TOKENS * DMODEL + 1)
#define NCHUNK   64      // scan chunks (256 tokens each)

typedef __attribute__((ext_vector_type(8))) short bf16x8;
typedef __attribute__((ext_vector_type(4))) float f32x4;

__device__ inline float bf2f(unsigned short u) {
    union { unsigned int i; float f; } v; v.i = ((unsigned int)u) << 16; return v.f;
}
__device__ inline unsigned short f2bf(float f) {
    __hip_bfloat16 h = __float2bfloat16(f);
    return *reinterpret_cast<unsigned short*>(&h);
}
// dtype-flexible load: f32i=1 -> float*, else bf16(ushort)*
__device__ inline float ldg(const void* p, size_t i, int f32i) {
    return f32i ? ((const float*)p)[i] : bf2f(((const ushort*)p)[i]);
}
__device__ inline float gelu_tanh(float x) {
    float u = 0.7978845608028654f * (x + 0.044715f * x * x * x);
    return 0.5f * x * (1.0f + tanhf(u));
}
__device__ inline void lds16(const void* g, void* l) {
    __builtin_amdgcn_global_load_lds((const __attribute__((address_space(1))) unsigned int*)g,
                                     (__attribute__((address_space(3))) unsigned int*)l, 16, 0, 0);
}

// ---------------- dtype detection ----------------
__global__ void detect_kernel(const ushort* __restrict__ xus, int* __restrict__ flag) {
    const int lane = threadIdx.x;  // 64
    int cnt = 0;
#pragma unroll
    for (int j = 0; j < 16; j++) {
        int p = lane * 16 + j;
        int eb = (xus[2 * p] >> 7) & 0xFF;
        cnt += (eb >= 100 && eb <= 140) ? 1 : 0;
    }
#pragma unroll
    for (int off = 32; off > 0; off >>= 1) cnt += __shfl_down(cnt, off, 64);
    if (lane == 0) flag[0] = (cnt < 512) ? 1 : 0;   // 1 = f32, 0 = bf16
}

// ---------------- zero the output ----------------
__global__ __launch_bounds__(256) void zero_kernel(void* __restrict__ out, const int* __restrict__ dflag) {
    const int f32i = *dflag;
    for (size_t i = (size_t)blockIdx.x * 256 + threadIdx.x; i < OUT_TOTAL; i += (size_t)gridDim.x * 256) {
        if (f32i) ((float*)out)[i] = 0.f; else ((ushort*)out)[i] = 0;
    }
}

// ---------------- x -> bf16 copy ----------------
__global__ __launch_bounds__(256) void convx_kernel(const void* __restrict__ x, const int* __restrict__ dflag,
                                                    ushort* __restrict__ xb) {
    const int f32i = *dflag;
    for (size_t i = (size_t)blockIdx.x * 256 + threadIdx.x; i < (size_t)S_TOKENS * DMODEL;
         i += (size_t)gridDim.x * 256)
        xb[i] = f32i ? f2bf(((const float*)x)[i]) : ((const ushort*)x)[i];
}

// ---------------- gating ----------------
__global__ __launch_bounds__(256) void gate_kernel(const void* __restrict__ x, const void* __restrict__ Wg,
                                                   const int* __restrict__ dflag,
                                                   float* __restrict__ gate1, float* __restrict__ gate2,
                                                   int* __restrict__ idx1, int* __restrict__ idx2,
                                                   float* __restrict__ bsum) {
    __shared__ float wgs[DMODEL * NEXP];   // 32 KB
    __shared__ float gsh[4][NEXP];
    const int t = threadIdx.x;
    const int f32i = *dflag;
    for (int i = t; i < DMODEL * NEXP; i += 256) wgs[i] = ldg(Wg, i, f32i);
    __syncthreads();
    const int wave = t >> 6, lane = t & 63;
    const int s = blockIdx.x * 4 + wave;
    float acc[NEXP];
#pragma unroll
    for (int e = 0; e < NEXP; e++) acc[e] = 0.f;
#pragma unroll
    for (int i = 0; i < 16; i++) {
        int d = i * 64 + lane;
        float xv = ldg(x, (size_t)s * DMODEL + d, f32i);
        const float* w = &wgs[d * NEXP];
#pragma unroll
        for (int e = 0; e < NEXP; e++) acc[e] += xv * w[e];
    }
#pragma unroll
    for (int off = 32; off > 0; off >>= 1)
#pragma unroll
        for (int e = 0; e < NEXP; e++) acc[e] += __shfl_down(acc[e], off, 64);
    if (lane == 0) {
        float mx = acc[0];
#pragma unroll
        for (int e = 1; e < NEXP; e++) mx = fmaxf(mx, acc[e]);
        float p[NEXP], se = 0.f;
#pragma unroll
        for (int e = 0; e < NEXP; e++) { p[e] = __expf(acc[e] - mx); se += p[e]; }
        float inv = 1.0f / se;
#pragma unroll
        for (int e = 0; e < NEXP; e++) p[e] *= inv;
        int i1 = 0; float g1v = p[0];
#pragma unroll
        for (int e = 1; e < NEXP; e++) if (p[e] > g1v) { g1v = p[e]; i1 = e; }
        int i2 = -1; float g2v = -1.0f;
#pragma unroll
        for (int e = 0; e < NEXP; e++) if (e != i1 && p[e] > g2v) { g2v = p[e]; i2 = e; }
        gate1[s] = g1v; gate2[s] = g2v; idx1[s] = i1; idx2[s] = i2;
#pragma unroll
        for (int e = 0; e < NEXP; e++) gsh[wave][e] = p[e];
    }
    __syncthreads();
    if (t < NEXP) bsum[blockIdx.x * NEXP + t] = gsh[0][t] + gsh[1][t] + gsh[2][t] + gsh[3][t];
}

// ---------------- parallel capacity scan ----------------
// Stage 1: per-256-token-chunk histograms of idx1/idx2, bsum partial sums, rowmap -1 fill.
__global__ __launch_bounds__(256) void hist_kernel(const int* __restrict__ idx1, const int* __restrict__ idx2,
                                                   const float* __restrict__ bsum,
                                                   int* __restrict__ c1, int* __restrict__ c2,
                                                   float* __restrict__ msumB, int* __restrict__ rowmap) {
    const int b = blockIdx.x, t = threadIdx.x;
    const int w = t >> 6, lane = t & 63;
    __shared__ int sc1[4][NEXP], sc2[4][NEXP];
    __shared__ float sm[256];

    // rowmap init (NEXP*CAP = 20480 entries over 64*256 threads)
    for (int i = b * 256 + t; i < NEXP * CAP; i += NCHUNK * 256) rowmap[i] = -1;

    const int s = b * 256 + w * 64 + lane;
    const int id1 = idx1[s], id2 = idx2[s];
#pragma unroll
    for (int e = 0; e < NEXP; e++) {
        unsigned long long m1 = __ballot(id1 == e);
        unsigned long long m2 = __ballot(id2 == e);
        if (lane == 0) { sc1[w][e] = __popcll(m1); sc2[w][e] = __popcll(m2); }
    }
    // bsum partial: this chunk covers 512 flat floats at offset b*512; expert = flat&7
    sm[t] = bsum[b * 512 + t] + bsum[b * 512 + 256 + t];
    __syncthreads();
    if (t < NEXP) {
        c1[b * NEXP + t] = sc1[0][t] + sc1[1][t] + sc1[2][t] + sc1[3][t];
        c2[b * NEXP + t] = sc2[0][t] + sc2[1][t] + sc2[2][t] + sc2[3][t];
        float ms = 0.f;
#pragma unroll
        for (int k = 0; k < 32; k++) ms += sm[t + NEXP * k];
        msumB[b * NEXP + t] = ms;
    }
}

// Stage 2: exclusive scan of chunk counts per expert; used1 = min(count1, CAP); loss.
__global__ void base_kernel(const int* __restrict__ c1, const int* __restrict__ c2,
                            const float* __restrict__ msumB, const int* __restrict__ dflag,
                            int* __restrict__ base1, int* __restrict__ base2, void* __restrict__ out) {
    const int lane = threadIdx.x;   // 64
    float contrib = 0.f;
    if (lane < NEXP) {
        int run = 0;
        for (int b = 0; b < NCHUNK; b++) { base1[b * NEXP + lane] = run; run += c1[b * NEXP + lane]; }
        const int count1 = run;
        int run2 = count1 < CAP ? count1 : CAP;   // used1 = min(count1, C)
        for (int b = 0; b < NCHUNK; b++) { base2[b * NEXP + lane] = run2; run2 += c2[b * NEXP + lane]; }
        float ms = 0.f;
        for (int b = 0; b < NCHUNK; b++) ms += msumB[b * NEXP + lane];
        contrib = (ms / (float)S_TOKENS) * ((float)count1 / (float)S_TOKENS);
    }
#pragma unroll
    for (int off = 4; off > 0; off >>= 1) contrib += __shfl_down(contrib, off, 64);
    if (lane == 0) {
        float L = 0.08f * contrib;   // 0.01 * mean(me*ce) * E*E
        if (*dflag) ((float*)out)[(size_t)S_TOKENS * DMODEL] = L;
        else        ((ushort*)out)[(size_t)S_TOKENS * DMODEL] = f2bf(L);
    }
}

// Stage 3: exact positions = chunk base + earlier-wave counts + within-wave ballot rank.
__global__ __launch_bounds__(256) void place_kernel(const int* __restrict__ idx1, const int* __restrict__ idx2,
                                                    const int* __restrict__ base1, const int* __restrict__ base2,
                                                    int* __restrict__ p1i, int* __restrict__ p2i,
                                                    int* __restrict__ rowmap) {
    const int b = blockIdx.x, t = threadIdx.x;
    const int w = t >> 6, lane = t & 63;
    const unsigned long long below = (1ull << lane) - 1ull;
    __shared__ int wc1[4][NEXP], wc2[4][NEXP];
    const int s = b * 256 + w * 64 + lane;
    const int id1 = idx1[s], id2 = idx2[s];
    int r1 = 0, r2 = 0;
#pragma unroll
    for (int e = 0; e < NEXP; e++) {
        unsigned long long m1 = __ballot(id1 == e);
        if (id1 == e) r1 = __popcll(m1 & below);
        unsigned long long m2 = __ballot(id2 == e);
        if (id2 == e) r2 = __popcll(m2 & below);
        if (lane == 0) { wc1[w][e] = __popcll(m1); wc2[w][e] = __popcll(m2); }
    }
    __syncthreads();
    int off1 = 0, off2 = 0;
#pragma unroll
    for (int ww = 0; ww < 3; ww++) {
        if (ww < w) { off1 += wc1[ww][id1]; off2 += wc2[ww][id2]; }
    }
    const int pos1 = base1[b * NEXP + id1] + off1 + r1;
    if (pos1 < CAP) { p1i[s] = pos1; rowmap[id1 * CAP + pos1] = s; } else p1i[s] = -1;
    const int pos2 = base2[b * NEXP + id2] + off2 + r2;
    if (pos2 < CAP) { p2i[s] = pos2; rowmap[id2 * CAP + pos2] = s; } else p2i[s] = -1;
}

// ---------------- transpose + convert: dst[c][r] (bf16) = src[srcBase + r*srcStride + c] ----------------
__global__ __launch_bounds__(256) void transpose_conv(const void* __restrict__ src, ushort* __restrict__ dst,
                                                      const int* __restrict__ dflag,
                                                      long srcBase, int srcStride, int dstStride) {
    __shared__ ushort tile[64][68];
    const int f32i = *dflag;
    const int c0 = blockIdx.x * 64, r0 = blockIdx.y * 64;
    const int tx = threadIdx.x & 15, ty = threadIdx.x >> 4;
#pragma unroll
    for (int k = 0; k < 4; k++) {
        int row = ty + 16 * k;
        size_t b = (size_t)srcBase + (size_t)(r0 + row) * srcStride + c0 + tx * 4;
#pragma unroll
        for (int j = 0; j < 4; j++) tile[row][tx * 4 + j] = f2bf(ldg(src, b + j, f32i));
    }
    __syncthreads();
#pragma unroll
    for (int k = 0; k < 4; k++) {
        int orow = ty + 16 * k;
        ushort4 v;
        v.x = tile[tx * 4 + 0][orow];
        v.y = tile[tx * 4 + 1][orow];
        v.z = tile[tx * 4 + 2][orow];
        v.w = tile[tx * 4 + 3][orow];
        *(ushort4*)(dst + (size_t)(c0 + orow) * dstStride + r0 + tx * 4) = v;
    }
}

// ---------------- GEMM1: h[2560, NC] = GELU(gather(xb)[2560,1024] @ T[NC,1024]^T + b1slice) ----------------
template<int NC>
__global__ __launch_bounds__(256) void gemm1_kernel(const ushort* __restrict__ xb,
                                                    const int* __restrict__ rowmapE,
                                                    const ushort* __restrict__ T,
                                                    const void* __restrict__ b1, long biasBase,
                                                    const int* __restrict__ dflag,
                                                    ushort* __restrict__ hout) {
    __shared__ ushort lA[128 * 32];
    __shared__ ushort lB[128 * 32];
    const int t = threadIdx.x;
    const int w = t >> 6, lane = t & 63;
    const int n0 = blockIdx.x * 128, m0 = blockIdx.y * 128;
    const int wr = w >> 1, wc = w & 1;
    const int l15 = lane & 15, quad = lane >> 4;

    int arow[2];
#pragma unroll
    for (int it = 0; it < 2; it++) {
        int r = (it * 2048 + w * 512 + lane * 8) >> 5;
        int rm = rowmapE[m0 + r];
        arow[it] = rm < 0 ? 0 : rm;
    }

    f32x4 acc[4][4];
#pragma unroll
    for (int i = 0; i < 4; i++)
#pragma unroll
        for (int j = 0; j < 4; j++) acc[i][j] = (f32x4){0.f, 0.f, 0.f, 0.f};

    for (int k0 = 0; k0 < DMODEL; k0 += 32) {
        __syncthreads();
#pragma unroll
        for (int it = 0; it < 2; it++) {
            int f = it * 2048 + w * 512 + lane * 8;
            int r = f >> 5, kk = f & 31;
            lds16(xb + (size_t)arow[it] * DMODEL + k0 + kk, &lA[it * 2048 + w * 512]);
            lds16(T + (size_t)(n0 + r) * DMODEL + k0 + kk, &lB[it * 2048 + w * 512]);
        }
        __syncthreads();
        bf16x8 af[4], bfr[4];
#pragma unroll
        for (int i = 0; i < 4; i++) af[i] = *(const bf16x8*)&lA[(wr * 64 + i * 16 + l15) * 32 + quad * 8];
#pragma unroll
        for (int j = 0; j < 4; j++) bfr[j] = *(const bf16x8*)&lB[(wc * 64 + j * 16 + l15) * 32 + quad * 8];
#pragma unroll
        for (int i = 0; i < 4; i++)
#pragma unroll
            for (int j = 0; j < 4; j++)
                acc[i][j] = __builtin_amdgcn_mfma_f32_16x16x32_bf16(af[i], bfr[j], acc[i][j], 0, 0, 0);
    }
    const int f32i = *dflag;
    float bv[4];
#pragma unroll
    for (int j = 0; j < 4; j++) bv[j] = ldg(b1, biasBase + n0 + wc * 64 + j * 16 + l15, f32i);
#pragma unroll
    for (int i = 0; i < 4; i++) {
        int row0 = m0 + wr * 64 + i * 16 + quad * 4;
#pragma unroll
        for (int j = 0; j < 4; j++) {
            int col = n0 + wc * 64 + j * 16 + l15;
#pragma unroll
            for (int r = 0; r < 4; r++)
                hout[(size_t)(row0 + r) * NC + col] = f2bf(gelu_tanh(acc[i][j][r] + bv[j]));
        }
    }
}

// ---------------- GEMM2: eoTile = h[2560,KC] @ T2[1024,KC]^T ; scatter-add w*(eo+b2) into out ----------------
template<int KC>
__global__ __launch_bounds__(256) void gemm2_kernel(const ushort* __restrict__ h,
                                                    const ushort* __restrict__ T2,
                                                    const void* __restrict__ b2, long b2Base,
                                                    const int* __restrict__ dflag,
                                                    const int* __restrict__ rowmapE,
                                                    const int* __restrict__ idx1,
                                                    const int* __restrict__ p1i, const int* __restrict__ p2i,
                                                    const float* __restrict__ gate1, const float* __restrict__ gate2,
                                                    int expert, int addB2, void* __restrict__ out) {
    __shared__ ushort lA[128 * 32];
    __shared__ ushort lB[128 * 32];
    const int t = threadIdx.x;
    const int w = t >> 6, lane = t & 63;
    const int n0 = blockIdx.x * 128, m0 = blockIdx.y * 128;
    const int wr = w >> 1, wc = w & 1;
    const int l15 = lane & 15, quad = lane >> 4;

    f32x4 acc[4][4];
#pragma unroll
    for (int i = 0; i < 4; i++)
#pragma unroll
        for (int j = 0; j < 4; j++) acc[i][j] = (f32x4){0.f, 0.f, 0.f, 0.f};

    for (int k0 = 0; k0 < KC; k0 += 32) {
        __syncthreads();
#pragma unroll
        for (int it = 0; it < 2; it++) {
            int f = it * 2048 + w * 512 + lane * 8;
            int r = f >> 5, kk = f & 31;
            lds16(h  + (size_t)(m0 + r) * KC + k0 + kk, &lA[it * 2048 + w * 512]);
            lds16(T2 + (size_t)(n0 + r) * KC + k0 + kk, &lB[it * 2048 + w * 512]);
        }
        __syncthreads();
        bf16x8 af[4], bfr[4];
#pragma unroll
        for (int i = 0; i < 4; i++) af[i] = *(const bf16x8*)&lA[(wr * 64 + i * 16 + l15) * 32 + quad * 8];
#pragma unroll
        for (int j = 0; j < 4; j++) bfr[j] = *(const bf16x8*)&lB[(wc * 64 + j * 16 + l15) * 32 + quad * 8];
#pragma unroll
        for (int i = 0; i < 4; i++)
#pragma unroll
            for (int j = 0; j < 4; j++)
                acc[i][j] = __builtin_amdgcn_mfma_f32_16x16x32_bf16(af[i], bfr[j], acc[i][j], 0, 0, 0);
    }
    const int f32i = *dflag;
    float b2v[4];
#pragma unroll
    for (int j = 0; j < 4; j++) b2v[j] = addB2 ? ldg(b2, b2Base + n0 + wc * 64 + j * 16 + l15, f32i) : 0.f;
#pragma unroll
    for (int i = 0; i < 4; i++) {
#pragma unroll
        for (int r = 0; r < 4; r++) {
            int row = m0 + wr * 64 + i * 16 + quad * 4 + r;
            int s = rowmapE[row];
            if (s < 0) continue;
            float g1 = gate1[s], g2 = gate2[s];
            float k1 = (p1i[s] >= 0) ? 1.f : 0.f, k2 = (p2i[s] >= 0) ? 1.f : 0.f;
            float denom = g1 * k1 + g2 * k2 + 1e-9f;
            float wgt = ((idx1[s] == expert) ? g1 : g2) / denom;
            size_t obase = (size_t)s * DMODEL;
#pragma unroll
            for (int j = 0; j < 4; j++) {
                int col = n0 + wc * 64 + j * 16 + l15;
                float contrib = wgt * (acc[i][j][r] + b2v[j]);
                size_t oi = obase + col;
                if (f32i) { float* po = (float*)out; po[oi] += contrib; }
                else { ushort* po = (ushort*)out; po[oi] = f2bf(bf2f(po[oi]) + contrib); }
            }
        }
    }
}

// ---------------- pipeline ----------------
template<int HC>
static void run_moe(const void* x, const void* Wg, const void* W1, const void* b1,
                    const void* W2, const void* b2, void* out, char* ws, hipStream_t stream) {
    int*   flag   = (int*)ws;
    int*   rowmap = (int*)(ws + 256);
    float* gate1  = (float*)(ws + 82176);
    float* gate2  = (float*)(ws + 147712);
    int*   idx1   = (int*)(ws + 213248);
    int*   idx2   = (int*)(ws + 278784);
    int*   p1i    = (int*)(ws + 344320);
    int*   p2i    = (int*)(ws + 409856);
    float* bsum   = (float*)(ws + 475392);       // +131072 -> 606464
    int*   c1     = (int*)(ws + 606464);         // 64*8*4 = 2048
    int*   c2     = (int*)(ws + 608512);
    float* msumB  = (float*)(ws + 610560);
    int*   base1  = (int*)(ws + 612608);
    int*   base2  = (int*)(ws + 614656);         // -> 616704 (< 655360, fits)
    ushort* xb    = (ushort*)(ws + 655360);      // 33,554,432 B
    ushort* h     = (ushort*)(ws + 655360 + 33554432);                       // 2560*HC*2
    ushort* T     = (ushort*)(ws + 655360 + 33554432 + (size_t)2560 * HC * 2); // 1024*HC*2

    detect_kernel<<<dim3(1), 64, 0, stream>>>((const ushort*)x, flag);
    zero_kernel<<<dim3(16384), 256, 0, stream>>>(out, flag);
    convx_kernel<<<dim3(8192), 256, 0, stream>>>(x, flag, xb);
    gate_kernel<<<dim3(S_TOKENS / 4), 256, 0, stream>>>(x, Wg, flag, gate1, gate2, idx1, idx2, bsum);
    hist_kernel<<<dim3(NCHUNK), 256, 0, stream>>>(idx1, idx2, bsum, c1, c2, msumB, rowmap);
    base_kernel<<<dim3(1), 64, 0, stream>>>(c1, c2, msumB, flag, base1, base2, out);
    place_kernel<<<dim3(NCHUNK), 256, 0, stream>>>(idx1, idx2, base1, base2, p1i, p2i, rowmap);

    for (int e = 0; e < NEXP; e++) {
        for (int c = 0; c < HFF / HC; c++) {
            const long hoff = (long)c * HC;
            // T <- W1[e][:, hoff:hoff+HC]^T  => [HC][1024]
            transpose_conv<<<dim3(HC / 64, DMODEL / 64), 256, 0, stream>>>(
                W1, T, flag, (long)e * DMODEL * HFF + hoff, HFF, DMODEL);
            gemm1_kernel<HC><<<dim3(HC / 128, CAP / 128), 256, 0, stream>>>(
                xb, rowmap + e * CAP, T, b1, (long)e * HFF + hoff, flag, h);
            // T <- W2[e][hoff:hoff+HC, :]^T  => [1024][HC]
            transpose_conv<<<dim3(DMODEL / 64, HC / 64), 256, 0, stream>>>(
                W2, T, flag, (long)e * HFF * DMODEL + hoff * DMODEL, DMODEL, HC);
            gemm2_kernel<HC><<<dim3(DMODEL / 128, CAP / 128), 256, 0, stream>>>(
                h, T, b2, (long)e * DMODEL, flag, rowmap + e * CAP,
                idx1, p1i, p2i, gate1, gate2, e, c == 0 ? 1 : 0, out);
        }
    }
}

// ---------------- launcher ----------------
extern "C" void kernel_launch(void* const* d_in, const int* in_sizes, int n_in,
                              void* d_out, int out_size, void* d_ws, size_t ws_size,
                              hipStream_t stream) {
    const void* x  = d_in[0];
    const void* Wg = d_in[1];
    const void* W1 = d_in[2];
    const void* b1 = d_in[3];
    const void* W2 = d_in[4];
    const void* b2 = d_in[5];
    char* ws = (char*)d_ws;

    // footprints: HC=4096 -> 63.6 MB, 2048 -> 48.9 MB, 1024 -> 41.5 MB, 512 -> 37.9 MB
    if (ws_size >= 64000000ull)      run_moe<4096>(x, Wg, W1, b1, W2, b2, d_out, ws, stream);
    else if (ws_size >= 49000000ull) run_moe<2048>(x, Wg, W1, b1, W2, b2, d_out, ws, stream);
    else if (ws_size >= 42000000ull) run_moe<1024>(x, Wg, W1, b1, W2, b2, d_out, ws, stream);
    else                             run_moe<512>(x, Wg, W1, b1, W2, b2, d_out, ws, stream);
}

// Round 2
// 1514.264 us; speedup vs baseline: 1.2275x; 1.0861x over previous
//
#include <hip/hip_runtime.h>
#include <hip/hip_bf16.h>

// ---------------- problem constants ----------------
#define S_TOKENS 16384   // B*N
#define DMODEL   1024
#define NEXP     8
#define HFF      4096
#define CAP      2560    // int(S*1.25/E)
#define OUT_TOTAL (S_TOKENS * DMODEL + 1)
#define NCHUNK   64      // scan chunks (256 tokens each)

typedef __attribute__((ext_vector_type(8))) short bf16x8;
typedef __attribute__((ext_vector_type(4))) float f32x4;

__device__ inline float bf2f(unsigned short u) {
    union { unsigned int i; float f; } v; v.i = ((unsigned int)u) << 16; return v.f;
}
__device__ inline unsigned short f2bf(float f) {
    __hip_bfloat16 h = __float2bfloat16(f);
    return *reinterpret_cast<unsigned short*>(&h);
}
// dtype-flexible load: f32i=1 -> float*, else bf16(ushort)*
__device__ inline float ldg(const void* p, size_t i, int f32i) {
    return f32i ? ((const float*)p)[i] : bf2f(((const ushort*)p)[i]);
}
__device__ inline float gelu_tanh(float x) {
    float u = 0.7978845608028654f * (x + 0.044715f * x * x * x);
    return 0.5f * x * (1.0f + tanhf(u));
}
__device__ inline void lds16(const void* g, void* l) {
    __builtin_amdgcn_global_load_lds((const __attribute__((address_space(1))) unsigned int*)g,
                                     (__attribute__((address_space(3))) unsigned int*)l, 16, 0, 0);
}

// ---------------- dtype detection ----------------
__global__ void detect_kernel(const ushort* __restrict__ xus, int* __restrict__ flag) {
    const int lane = threadIdx.x;  // 64
    int cnt = 0;
#pragma unroll
    for (int j = 0; j < 16; j++) {
        int p = lane * 16 + j;
        int eb = (xus[2 * p] >> 7) & 0xFF;
        cnt += (eb >= 100 && eb <= 140) ? 1 : 0;
    }
#pragma unroll
    for (int off = 32; off > 0; off >>= 1) cnt += __shfl_down(cnt, off, 64);
    if (lane == 0) flag[0] = (cnt < 512) ? 1 : 0;   // 1 = f32, 0 = bf16
}

// ---------------- zero the output ----------------
__global__ __launch_bounds__(256) void zero_kernel(void* __restrict__ out, const int* __restrict__ dflag) {
    const int f32i = *dflag;
    for (size_t i = (size_t)blockIdx.x * 256 + threadIdx.x; i < OUT_TOTAL; i += (size_t)gridDim.x * 256) {
        if (f32i) ((float*)out)[i] = 0.f; else ((ushort*)out)[i] = 0;
    }
}

// ---------------- zero the f32 expert-output staging ----------------
__global__ __launch_bounds__(256) void zeroeo_kernel(float* __restrict__ p) {
    for (size_t i = (size_t)blockIdx.x * 256 + threadIdx.x; i < (size_t)CAP * DMODEL; i += (size_t)gridDim.x * 256)
        p[i] = 0.f;
}

// ---------------- x -> bf16 copy ----------------
__global__ __launch_bounds__(256) void convx_kernel(const void* __restrict__ x, const int* __restrict__ dflag,
                                                    ushort* __restrict__ xb) {
    const int f32i = *dflag;
    for (size_t i = (size_t)blockIdx.x * 256 + threadIdx.x; i < (size_t)S_TOKENS * DMODEL;
         i += (size_t)gridDim.x * 256)
        xb[i] = f32i ? f2bf(((const float*)x)[i]) : ((const ushort*)x)[i];
}

// ---------------- gating ----------------
__global__ __launch_bounds__(256) void gate_kernel(const void* __restrict__ x, const void* __restrict__ Wg,
                                                   const int* __restrict__ dflag,
                                                   float* __restrict__ gate1, float* __restrict__ gate2,
                                                   int* __restrict__ idx1, int* __restrict__ idx2,
                                                   float* __restrict__ bsum) {
    __shared__ float wgs[DMODEL * NEXP];   // 32 KB
    __shared__ float gsh[4][NEXP];
    const int t = threadIdx.x;
    const int f32i = *dflag;
    for (int i = t; i < DMODEL * NEXP; i += 256) wgs[i] = ldg(Wg, i, f32i);
    __syncthreads();
    const int wave = t >> 6, lane = t & 63;
    const int s = blockIdx.x * 4 + wave;
    float acc[NEXP];
#pragma unroll
    for (int e = 0; e < NEXP; e++) acc[e] = 0.f;
#pragma unroll
    for (int i = 0; i < 16; i++) {
        int d = i * 64 + lane;
        float xv = ldg(x, (size_t)s * DMODEL + d, f32i);
        const float* w = &wgs[d * NEXP];
#pragma unroll
        for (int e = 0; e < NEXP; e++) acc[e] += xv * w[e];
    }
#pragma unroll
    for (int off = 32; off > 0; off >>= 1)
#pragma unroll
        for (int e = 0; e < NEXP; e++) acc[e] += __shfl_down(acc[e], off, 64);
    if (lane == 0) {
        float mx = acc[0];
#pragma unroll
        for (int e = 1; e < NEXP; e++) mx = fmaxf(mx, acc[e]);
        float p[NEXP], se = 0.f;
#pragma unroll
        for (int e = 0; e < NEXP; e++) { p[e] = __expf(acc[e] - mx); se += p[e]; }
        float inv = 1.0f / se;
#pragma unroll
        for (int e = 0; e < NEXP; e++) p[e] *= inv;
        int i1 = 0; float g1v = p[0];
#pragma unroll
        for (int e = 1; e < NEXP; e++) if (p[e] > g1v) { g1v = p[e]; i1 = e; }
        int i2 = -1; float g2v = -1.0f;
#pragma unroll
        for (int e = 0; e < NEXP; e++) if (e != i1 && p[e] > g2v) { g2v = p[e]; i2 = e; }
        gate1[s] = g1v; gate2[s] = g2v; idx1[s] = i1; idx2[s] = i2;
#pragma unroll
        for (int e = 0; e < NEXP; e++) gsh[wave][e] = p[e];
    }
    __syncthreads();
    if (t < NEXP) bsum[blockIdx.x * NEXP + t] = gsh[0][t] + gsh[1][t] + gsh[2][t] + gsh[3][t];
}

// ---------------- parallel capacity scan ----------------
__global__ __launch_bounds__(256) void hist_kernel(const int* __restrict__ idx1, const int* __restrict__ idx2,
                                                   const float* __restrict__ bsum,
                                                   int* __restrict__ c1, int* __restrict__ c2,
                                                   float* __restrict__ msumB, int* __restrict__ rowmap) {
    const int b = blockIdx.x, t = threadIdx.x;
    const int w = t >> 6, lane = t & 63;
    __shared__ int sc1[4][NEXP], sc2[4][NEXP];
    __shared__ float sm[256];

    for (int i = b * 256 + t; i < NEXP * CAP; i += NCHUNK * 256) rowmap[i] = -1;

    const int s = b * 256 + w * 64 + lane;
    const int id1 = idx1[s], id2 = idx2[s];
#pragma unroll
    for (int e = 0; e < NEXP; e++) {
        unsigned long long m1 = __ballot(id1 == e);
        unsigned long long m2 = __ballot(id2 == e);
        if (lane == 0) { sc1[w][e] = __popcll(m1); sc2[w][e] = __popcll(m2); }
    }
    sm[t] = bsum[b * 512 + t] + bsum[b * 512 + 256 + t];
    __syncthreads();
    if (t < NEXP) {
        c1[b * NEXP + t] = sc1[0][t] + sc1[1][t] + sc1[2][t] + sc1[3][t];
        c2[b * NEXP + t] = sc2[0][t] + sc2[1][t] + sc2[2][t] + sc2[3][t];
        float ms = 0.f;
#pragma unroll
        for (int k = 0; k < 32; k++) ms += sm[t + NEXP * k];
        msumB[b * NEXP + t] = ms;
    }
}

__global__ void base_kernel(const int* __restrict__ c1, const int* __restrict__ c2,
                            const float* __restrict__ msumB, const int* __restrict__ dflag,
                            int* __restrict__ base1, int* __restrict__ base2, void* __restrict__ out) {
    const int lane = threadIdx.x;   // 64
    float contrib = 0.f;
    if (lane < NEXP) {
        int run = 0;
        for (int b = 0; b < NCHUNK; b++) { base1[b * NEXP + lane] = run; run += c1[b * NEXP + lane]; }
        const int count1 = run;
        int run2 = count1 < CAP ? count1 : CAP;   // used1 = min(count1, C)
        for (int b = 0; b < NCHUNK; b++) { base2[b * NEXP + lane] = run2; run2 += c2[b * NEXP + lane]; }
        float ms = 0.f;
        for (int b = 0; b < NCHUNK; b++) ms += msumB[b * NEXP + lane];
        contrib = (ms / (float)S_TOKENS) * ((float)count1 / (float)S_TOKENS);
    }
#pragma unroll
    for (int off = 4; off > 0; off >>= 1) contrib += __shfl_down(contrib, off, 64);
    if (lane == 0) {
        float L = 0.08f * contrib;   // 0.01 * mean(me*ce) * E*E
        if (*dflag) ((float*)out)[(size_t)S_TOKENS * DMODEL] = L;
        else        ((ushort*)out)[(size_t)S_TOKENS * DMODEL] = f2bf(L);
    }
}

__global__ __launch_bounds__(256) void place_kernel(const int* __restrict__ idx1, const int* __restrict__ idx2,
                                                    const int* __restrict__ base1, const int* __restrict__ base2,
                                                    int* __restrict__ p1i, int* __restrict__ p2i,
                                                    int* __restrict__ rowmap) {
    const int b = blockIdx.x, t = threadIdx.x;
    const int w = t >> 6, lane = t & 63;
    const unsigned long long below = (1ull << lane) - 1ull;
    __shared__ int wc1[4][NEXP], wc2[4][NEXP];
    const int s = b * 256 + w * 64 + lane;
    const int id1 = idx1[s], id2 = idx2[s];
    int r1 = 0, r2 = 0;
#pragma unroll
    for (int e = 0; e < NEXP; e++) {
        unsigned long long m1 = __ballot(id1 == e);
        if (id1 == e) r1 = __popcll(m1 & below);
        unsigned long long m2 = __ballot(id2 == e);
        if (id2 == e) r2 = __popcll(m2 & below);
        if (lane == 0) { wc1[w][e] = __popcll(m1); wc2[w][e] = __popcll(m2); }
    }
    __syncthreads();
    int off1 = 0, off2 = 0;
#pragma unroll
    for (int ww = 0; ww < 3; ww++) {
        if (ww < w) { off1 += wc1[ww][id1]; off2 += wc2[ww][id2]; }
    }
    const int pos1 = base1[b * NEXP + id1] + off1 + r1;
    if (pos1 < CAP) { p1i[s] = pos1; rowmap[id1 * CAP + pos1] = s; } else p1i[s] = -1;
    const int pos2 = base2[b * NEXP + id2] + off2 + r2;
    if (pos2 < CAP) { p2i[s] = pos2; rowmap[id2 * CAP + pos2] = s; } else p2i[s] = -1;
}

// ---------------- transpose + convert: dst[c][r] (bf16) = src[srcBase + r*srcStride + c] ----------------
__global__ __launch_bounds__(256) void transpose_conv(const void* __restrict__ src, ushort* __restrict__ dst,
                                                      const int* __restrict__ dflag,
                                                      long srcBase, int srcStride, int dstStride) {
    __shared__ ushort tile[64][68];
    const int f32i = *dflag;
    const int c0 = blockIdx.x * 64, r0 = blockIdx.y * 64;
    const int tx = threadIdx.x & 15, ty = threadIdx.x >> 4;
#pragma unroll
    for (int k = 0; k < 4; k++) {
        int row = ty + 16 * k;
        size_t b = (size_t)srcBase + (size_t)(r0 + row) * srcStride + c0 + tx * 4;
#pragma unroll
        for (int j = 0; j < 4; j++) tile[row][tx * 4 + j] = f2bf(ldg(src, b + j, f32i));
    }
    __syncthreads();
#pragma unroll
    for (int k = 0; k < 4; k++) {
        int orow = ty + 16 * k;
        ushort4 v;
        v.x = tile[tx * 4 + 0][orow];
        v.y = tile[tx * 4 + 1][orow];
        v.z = tile[tx * 4 + 2][orow];
        v.w = tile[tx * 4 + 3][orow];
        *(ushort4*)(dst + (size_t)(c0 + orow) * dstStride + r0 + tx * 4) = v;
    }
}

// ---------------- GEMM1: h[2560, NC] = GELU(gather(xb)[2560,1024] @ T[NC,1024]^T + b1slice) ----------------
// LDS bank-conflict fix (T2-style): linear LDS dest (global_load_lds), inverse-swizzled global source,
// swizzled ds_read. Swizzle: phys = logical ^ (((logical>>6)&3)<<3) in elements (involution).
template<int NC>
__global__ __launch_bounds__(256) void gemm1_kernel(const ushort* __restrict__ xb,
                                                    const int* __restrict__ rowmapE,
                                                    const ushort* __restrict__ T,
                                                    const void* __restrict__ b1, long biasBase,
                                                    const int* __restrict__ dflag,
                                                    ushort* __restrict__ hout) {
    __shared__ ushort lA[128 * 32];
    __shared__ ushort lB[128 * 32];
    const int t = threadIdx.x;
    const int w = t >> 6, lane = t & 63;
    const int n0 = blockIdx.x * 128, m0 = blockIdx.y * 128;
    const int wr = w >> 1, wc = w & 1;
    const int l15 = lane & 15, quad = lane >> 4;
    const int swz = (lane >> 3) & 3;                 // staging source swizzle
    const int q2 = quad ^ ((l15 >> 1) & 3);          // read-side swizzle

    int arow[2];
#pragma unroll
    for (int it = 0; it < 2; it++) {
        int r = (it * 2048 + w * 512 + lane * 8) >> 5;
        int rm = rowmapE[m0 + r];
        arow[it] = rm < 0 ? 0 : rm;
    }

    f32x4 acc[4][4];
#pragma unroll
    for (int i = 0; i < 4; i++)
#pragma unroll
        for (int j = 0; j < 4; j++) acc[i][j] = (f32x4){0.f, 0.f, 0.f, 0.f};

    for (int k0 = 0; k0 < DMODEL; k0 += 32) {
        __syncthreads();
#pragma unroll
        for (int it = 0; it < 2; it++) {
            int f = it * 2048 + w * 512 + lane * 8;
            int r = f >> 5, kk = (f & 31) ^ (swz << 3);
            lds16(xb + (size_t)arow[it] * DMODEL + k0 + kk, &lA[it * 2048 + w * 512]);
            lds16(T + (size_t)(n0 + r) * DMODEL + k0 + kk, &lB[it * 2048 + w * 512]);
        }
        __syncthreads();
        bf16x8 af[4], bfr[4];
#pragma unroll
        for (int i = 0; i < 4; i++) af[i] = *(const bf16x8*)&lA[(wr * 64 + i * 16 + l15) * 32 + q2 * 8];
#pragma unroll
        for (int j = 0; j < 4; j++) bfr[j] = *(const bf16x8*)&lB[(wc * 64 + j * 16 + l15) * 32 + q2 * 8];
#pragma unroll
        for (int i = 0; i < 4; i++)
#pragma unroll
            for (int j = 0; j < 4; j++)
                acc[i][j] = __builtin_amdgcn_mfma_f32_16x16x32_bf16(af[i], bfr[j], acc[i][j], 0, 0, 0);
    }
    const int f32i = *dflag;
    float bv[4];
#pragma unroll
    for (int j = 0; j < 4; j++) bv[j] = ldg(b1, biasBase + n0 + wc * 64 + j * 16 + l15, f32i);
#pragma unroll
    for (int i = 0; i < 4; i++) {
        int row0 = m0 + wr * 64 + i * 16 + quad * 4;
#pragma unroll
        for (int j = 0; j < 4; j++) {
            int col = n0 + wc * 64 + j * 16 + l15;
#pragma unroll
            for (int r = 0; r < 4; r++)
                hout[(size_t)(row0 + r) * NC + col] = f2bf(gelu_tanh(acc[i][j][r] + bv[j]));
        }
    }
}

// ---------------- GEMM2 split-K: eo32[2560,1024] += h[2560,KC] @ T2[1024,KC]^T (f32 atomics) ----------------
template<int KC>
__global__ __launch_bounds__(256) void gemm2s_kernel(const ushort* __restrict__ h,
                                                     const ushort* __restrict__ T2,
                                                     float* __restrict__ eo32) {
    __shared__ ushort lA[128 * 32];
    __shared__ ushort lB[128 * 32];
    const int t = threadIdx.x;
    const int w = t >> 6, lane = t & 63;
    const int n0 = blockIdx.x * 128, m0 = blockIdx.y * 128;
    const int kbeg = blockIdx.z * 1024;
    const int wr = w >> 1, wc = w & 1;
    const int l15 = lane & 15, quad = lane >> 4;
    const int swz = (lane >> 3) & 3;
    const int q2 = quad ^ ((l15 >> 1) & 3);

    f32x4 acc[4][4];
#pragma unroll
    for (int i = 0; i < 4; i++)
#pragma unroll
        for (int j = 0; j < 4; j++) acc[i][j] = (f32x4){0.f, 0.f, 0.f, 0.f};

    for (int k0 = kbeg; k0 < kbeg + 1024; k0 += 32) {
        __syncthreads();
#pragma unroll
        for (int it = 0; it < 2; it++) {
            int f = it * 2048 + w * 512 + lane * 8;
            int r = f >> 5, kk = (f & 31) ^ (swz << 3);
            lds16(h  + (size_t)(m0 + r) * KC + k0 + kk, &lA[it * 2048 + w * 512]);
            lds16(T2 + (size_t)(n0 + r) * KC + k0 + kk, &lB[it * 2048 + w * 512]);
        }
        __syncthreads();
        bf16x8 af[4], bfr[4];
#pragma unroll
        for (int i = 0; i < 4; i++) af[i] = *(const bf16x8*)&lA[(wr * 64 + i * 16 + l15) * 32 + q2 * 8];
#pragma unroll
        for (int j = 0; j < 4; j++) bfr[j] = *(const bf16x8*)&lB[(wc * 64 + j * 16 + l15) * 32 + q2 * 8];
#pragma unroll
        for (int i = 0; i < 4; i++)
#pragma unroll
            for (int j = 0; j < 4; j++)
                acc[i][j] = __builtin_amdgcn_mfma_f32_16x16x32_bf16(af[i], bfr[j], acc[i][j], 0, 0, 0);
    }
#pragma unroll
    for (int i = 0; i < 4; i++) {
#pragma unroll
        for (int r = 0; r < 4; r++) {
            int row = m0 + wr * 64 + i * 16 + quad * 4 + r;
#pragma unroll
            for (int j = 0; j < 4; j++) {
                int col = n0 + wc * 64 + j * 16 + l15;
                atomicAdd(&eo32[(size_t)row * DMODEL + col], acc[i][j][r]);
            }
        }
    }
}

// ---------------- combine: out[s] += wgt * (eo32[r] + b2) via rowmap gather ----------------
__global__ __launch_bounds__(256) void combine_kernel(const float* __restrict__ eo32, const void* __restrict__ b2,
                                                      long b2Base, const int* __restrict__ dflag,
                                                      const int* __restrict__ rowmapE, const int* __restrict__ idx1,
                                                      const int* __restrict__ p1i, const int* __restrict__ p2i,
                                                      const float* __restrict__ gate1, const float* __restrict__ gate2,
                                                      int expert, void* __restrict__ out) {
    const int t = threadIdx.x;
    const int f32i = *dflag;
    const int c0 = t * 4;
    float bv[4];
#pragma unroll
    for (int j = 0; j < 4; j++) bv[j] = ldg(b2, b2Base + c0 + j, f32i);
    for (int r = blockIdx.x; r < CAP; r += gridDim.x) {
        int s = rowmapE[r];
        if (s < 0) continue;
        float g1 = gate1[s], g2 = gate2[s];
        float k1 = (p1i[s] >= 0) ? 1.f : 0.f, k2 = (p2i[s] >= 0) ? 1.f : 0.f;
        float denom = g1 * k1 + g2 * k2 + 1e-9f;
        float wgt = ((idx1[s] == expert) ? g1 : g2) / denom;
        float4 ev = *(const float4*)&eo32[(size_t)r * DMODEL + c0];
        size_t oi = (size_t)s * DMODEL + c0;
        if (f32i) {
            float4* po = (float4*)((float*)out + oi);
            float4 ov = *po;
            ov.x += wgt * (ev.x + bv[0]); ov.y += wgt * (ev.y + bv[1]);
            ov.z += wgt * (ev.z + bv[2]); ov.w += wgt * (ev.w + bv[3]);
            *po = ov;
        } else {
            ushort* po = (ushort*)out + oi;
            ushort4 ov = *(ushort4*)po;
            ov.x = f2bf(bf2f(ov.x) + wgt * (ev.x + bv[0]));
            ov.y = f2bf(bf2f(ov.y) + wgt * (ev.y + bv[1]));
            ov.z = f2bf(bf2f(ov.z) + wgt * (ev.z + bv[2]));
            ov.w = f2bf(bf2f(ov.w) + wgt * (ev.w + bv[3]));
            *(ushort4*)po = ov;
        }
    }
}

// ---------------- legacy GEMM2 (fallback paths only) ----------------
template<int KC>
__global__ __launch_bounds__(256) void gemm2_kernel(const ushort* __restrict__ h,
                                                    const ushort* __restrict__ T2,
                                                    const void* __restrict__ b2, long b2Base,
                                                    const int* __restrict__ dflag,
                                                    const int* __restrict__ rowmapE,
                                                    const int* __restrict__ idx1,
                                                    const int* __restrict__ p1i, const int* __restrict__ p2i,
                                                    const float* __restrict__ gate1, const float* __restrict__ gate2,
                                                    int expert, int addB2, void* __restrict__ out) {
    __shared__ ushort lA[128 * 32];
    __shared__ ushort lB[128 * 32];
    const int t = threadIdx.x;
    const int w = t >> 6, lane = t & 63;
    const int n0 = blockIdx.x * 128, m0 = blockIdx.y * 128;
    const int wr = w >> 1, wc = w & 1;
    const int l15 = lane & 15, quad = lane >> 4;

    f32x4 acc[4][4];
#pragma unroll
    for (int i = 0; i < 4; i++)
#pragma unroll
        for (int j = 0; j < 4; j++) acc[i][j] = (f32x4){0.f, 0.f, 0.f, 0.f};

    for (int k0 = 0; k0 < KC; k0 += 32) {
        __syncthreads();
#pragma unroll
        for (int it = 0; it < 2; it++) {
            int f = it * 2048 + w * 512 + lane * 8;
            int r = f >> 5, kk = f & 31;
            lds16(h  + (size_t)(m0 + r) * KC + k0 + kk, &lA[it * 2048 + w * 512]);
            lds16(T2 + (size_t)(n0 + r) * KC + k0 + kk, &lB[it * 2048 + w * 512]);
        }
        __syncthreads();
        bf16x8 af[4], bfr[4];
#pragma unroll
        for (int i = 0; i < 4; i++) af[i] = *(const bf16x8*)&lA[(wr * 64 + i * 16 + l15) * 32 + quad * 8];
#pragma unroll
        for (int j = 0; j < 4; j++) bfr[j] = *(const bf16x8*)&lB[(wc * 64 + j * 16 + l15) * 32 + quad * 8];
#pragma unroll
        for (int i = 0; i < 4; i++)
#pragma unroll
            for (int j = 0; j < 4; j++)
                acc[i][j] = __builtin_amdgcn_mfma_f32_16x16x32_bf16(af[i], bfr[j], acc[i][j], 0, 0, 0);
    }
    const int f32i = *dflag;
    float b2v[4];
#pragma unroll
    for (int j = 0; j < 4; j++) b2v[j] = addB2 ? ldg(b2, b2Base + n0 + wc * 64 + j * 16 + l15, f32i) : 0.f;
#pragma unroll
    for (int i = 0; i < 4; i++) {
#pragma unroll
        for (int r = 0; r < 4; r++) {
            int row = m0 + wr * 64 + i * 16 + quad * 4 + r;
            int s = rowmapE[row];
            if (s < 0) continue;
            float g1 = gate1[s], g2 = gate2[s];
            float k1 = (p1i[s] >= 0) ? 1.f : 0.f, k2 = (p2i[s] >= 0) ? 1.f : 0.f;
            float denom = g1 * k1 + g2 * k2 + 1e-9f;
            float wgt = ((idx1[s] == expert) ? g1 : g2) / denom;
            size_t obase = (size_t)s * DMODEL;
#pragma unroll
            for (int j = 0; j < 4; j++) {
                int col = n0 + wc * 64 + j * 16 + l15;
                float contrib = wgt * (acc[i][j][r] + b2v[j]);
                size_t oi = obase + col;
                if (f32i) { float* po = (float*)out; po[oi] += contrib; }
                else { ushort* po = (ushort*)out; po[oi] = f2bf(bf2f(po[oi]) + contrib); }
            }
        }
    }
}

// ---------------- shared prologue ----------------
struct WsPtrs {
    int *flag, *rowmap, *idx1, *idx2, *p1i, *p2i, *c1, *c2, *base1, *base2;
    float *gate1, *gate2, *bsum, *msumB;
    ushort* xb;
};
static WsPtrs ws_ptrs(char* ws) {
    WsPtrs p;
    p.flag   = (int*)ws;
    p.rowmap = (int*)(ws + 256);
    p.gate1  = (float*)(ws + 82176);
    p.gate2  = (float*)(ws + 147712);
    p.idx1   = (int*)(ws + 213248);
    p.idx2   = (int*)(ws + 278784);
    p.p1i    = (int*)(ws + 344320);
    p.p2i    = (int*)(ws + 409856);
    p.bsum   = (float*)(ws + 475392);
    p.c1     = (int*)(ws + 606464);
    p.c2     = (int*)(ws + 608512);
    p.msumB  = (float*)(ws + 610560);
    p.base1  = (int*)(ws + 612608);
    p.base2  = (int*)(ws + 614656);
    p.xb     = (ushort*)(ws + 655360);   // 33,554,432 B
    return p;
}
static void prologue(const void* x, const void* Wg, const WsPtrs& p, void* out, hipStream_t stream) {
    detect_kernel<<<dim3(1), 64, 0, stream>>>((const ushort*)x, p.flag);
    zero_kernel<<<dim3(16384), 256, 0, stream>>>(out, p.flag);
    convx_kernel<<<dim3(8192), 256, 0, stream>>>(x, p.flag, p.xb);
    gate_kernel<<<dim3(S_TOKENS / 4), 256, 0, stream>>>(x, Wg, p.flag, p.gate1, p.gate2, p.idx1, p.idx2, p.bsum);
    hist_kernel<<<dim3(NCHUNK), 256, 0, stream>>>(p.idx1, p.idx2, p.bsum, p.c1, p.c2, p.msumB, p.rowmap);
    base_kernel<<<dim3(1), 64, 0, stream>>>(p.c1, p.c2, p.msumB, p.flag, p.base1, p.base2, out);
    place_kernel<<<dim3(NCHUNK), 256, 0, stream>>>(p.idx1, p.idx2, p.base1, p.base2, p.p1i, p.p2i, p.rowmap);
}

// ---------------- design A: full-H per expert (ws >= ~74.1 MB) ----------------
static void run_moe_a(const void* x, const void* Wg, const void* W1, const void* b1,
                      const void* W2, const void* b2, void* out, char* ws, hipStream_t stream) {
    WsPtrs p = ws_ptrs(ws);
    ushort* h    = (ushort*)(ws + 655360 + 33554432);            // 2560*4096*2 = 20,971,520
    ushort* T    = (ushort*)(ws + 655360 + 33554432 + 20971520); // 8,388,608 (T1 then T2)
    float*  eo32 = (float*)(ws + 655360 + 33554432 + 20971520 + 8388608); // 10,485,760 -> end 74,055,680

    prologue(x, Wg, p, out, stream);
    for (int e = 0; e < NEXP; e++) {
        transpose_conv<<<dim3(HFF / 64, DMODEL / 64), 256, 0, stream>>>(
            W1, T, p.flag, (long)e * DMODEL * HFF, HFF, DMODEL);          // T1 [4096][1024]
        gemm1_kernel<HFF><<<dim3(HFF / 128, CAP / 128), 256, 0, stream>>>(
            p.xb, p.rowmap + e * CAP, T, b1, (long)e * HFF, p.flag, h);
        zeroeo_kernel<<<dim3(2048), 256, 0, stream>>>(eo32);
        transpose_conv<<<dim3(DMODEL / 64, HFF / 64), 256, 0, stream>>>(
            W2, T, p.flag, (long)e * HFF * DMODEL, DMODEL, HFF);          // T2 [1024][4096]
        gemm2s_kernel<HFF><<<dim3(DMODEL / 128, CAP / 128, HFF / 1024), 256, 0, stream>>>(h, T, eo32);
        combine_kernel<<<dim3(1280), 256, 0, stream>>>(
            eo32, b2, (long)e * DMODEL, p.flag, p.rowmap + e * CAP,
            p.idx1, p.p1i, p.p2i, p.gate1, p.gate2, e, out);
    }
}

// ---------------- design B: H chunked at 2048 (ws >= ~59.4 MB) ----------------
static void run_moe_b(const void* x, const void* Wg, const void* W1, const void* b1,
                      const void* W2, const void* b2, void* out, char* ws, hipStream_t stream) {
    WsPtrs p = ws_ptrs(ws);
    const int HC = 2048;
    ushort* h    = (ushort*)(ws + 655360 + 33554432);            // 2560*2048*2 = 10,485,760
    ushort* T    = (ushort*)(ws + 655360 + 33554432 + 10485760); // 4,194,304 (T1c / T2c)
    float*  eo32 = (float*)(ws + 655360 + 33554432 + 10485760 + 4194304); // 10,485,760 -> end 59,375,616

    prologue(x, Wg, p, out, stream);
    for (int e = 0; e < NEXP; e++) {
        zeroeo_kernel<<<dim3(2048), 256, 0, stream>>>(eo32);
        for (int c = 0; c < HFF / HC; c++) {
            const long hoff = (long)c * HC;
            transpose_conv<<<dim3(HC / 64, DMODEL / 64), 256, 0, stream>>>(
                W1, T, p.flag, (long)e * DMODEL * HFF + hoff, HFF, DMODEL);
            gemm1_kernel<HC><<<dim3(HC / 128, CAP / 128), 256, 0, stream>>>(
                p.xb, p.rowmap + e * CAP, T, b1, (long)e * HFF + hoff, p.flag, h);
            transpose_conv<<<dim3(DMODEL / 64, HC / 64), 256, 0, stream>>>(
                W2, T, p.flag, (long)e * HFF * DMODEL + hoff * DMODEL, DMODEL, HC);
            gemm2s_kernel<HC><<<dim3(DMODEL / 128, CAP / 128, HC / 1024), 256, 0, stream>>>(h, T, eo32);
        }
        combine_kernel<<<dim3(1280), 256, 0, stream>>>(
            eo32, b2, (long)e * DMODEL, p.flag, p.rowmap + e * CAP,
            p.idx1, p.p1i, p.p2i, p.gate1, p.gate2, e, out);
    }
}

// ---------------- legacy pipeline (small ws fallback) ----------------
template<int HC>
static void run_moe(const void* x, const void* Wg, const void* W1, const void* b1,
                    const void* W2, const void* b2, void* out, char* ws, hipStream_t stream) {
    WsPtrs p = ws_ptrs(ws);
    ushort* h = (ushort*)(ws + 655360 + 33554432);                         // 2560*HC*2
    ushort* T = (ushort*)(ws + 655360 + 33554432 + (size_t)2560 * HC * 2); // 1024*HC*2

    prologue(x, Wg, p, out, stream);
    for (int e = 0; e < NEXP; e++) {
        for (int c = 0; c < HFF / HC; c++) {
            const long hoff = (long)c * HC;
            transpose_conv<<<dim3(HC / 64, DMODEL / 64), 256, 0, stream>>>(
                W1, T, p.flag, (long)e * DMODEL * HFF + hoff, HFF, DMODEL);
            gemm1_kernel<HC><<<dim3(HC / 128, CAP / 128), 256, 0, stream>>>(
                p.xb, p.rowmap + e * CAP, T, b1, (long)e * HFF + hoff, p.flag, h);
            transpose_conv<<<dim3(DMODEL / 64, HC / 64), 256, 0, stream>>>(
                W2, T, p.flag, (long)e * HFF * DMODEL + hoff * DMODEL, DMODEL, HC);
            gemm2_kernel<HC><<<dim3(DMODEL / 128, CAP / 128), 256, 0, stream>>>(
                h, T, b2, (long)e * DMODEL, p.flag, p.rowmap + e * CAP,
                p.idx1, p.p1i, p.p2i, p.gate1, p.gate2, e, c == 0 ? 1 : 0, out);
        }
    }
}

// ---------------- launcher ----------------
extern "C" void kernel_launch(void* const* d_in, const int* in_sizes, int n_in,
                              void* d_out, int out_size, void* d_ws, size_t ws_size,
                              hipStream_t stream) {
    const void* x  = d_in[0];
    const void* Wg = d_in[1];
    const void* W1 = d_in[2];
    const void* b1 = d_in[3];
    const void* W2 = d_in[4];
    const void* b2 = d_in[5];
    char* ws = (char*)d_ws;

    if (ws_size >= 74200000ull)      run_moe_a(x, Wg, W1, b1, W2, b2, d_out, ws, stream);      // 74.06 MB
    else if (ws_size >= 59500000ull) run_moe_b(x, Wg, W1, b1, W2, b2, d_out, ws, stream);      // 59.38 MB
    else if (ws_size >= 49000000ull) run_moe<2048>(x, Wg, W1, b1, W2, b2, d_out, ws, stream);
    else if (ws_size >= 42000000ull) run_moe<1024>(x, Wg, W1, b1, W2, b2, d_out, ws, stream);
    else                             run_moe<512>(x, Wg, W1, b1, W2, b2, d_out, ws, stream);
}

// Round 3
// 1197.234 us; speedup vs baseline: 1.5526x; 1.2648x over previous
//
#include <hip/hip_runtime.h>
#include <hip/hip_bf16.h>

// ---------------- problem constants ----------------
#define S_TOKENS 16384   // B*N
#define DMODEL   1024
#define NEXP     8
#define HFF      4096
#define CAP      2560    // int(S*1.25/E)
#define OUT_TOTAL (S_TOKENS * DMODEL + 1)
#define NCHUNK   64      // scan chunks (256 tokens each)

typedef __attribute__((ext_vector_type(8))) short bf16x8;
typedef __attribute__((ext_vector_type(4))) float f32x4;

__device__ inline float bf2f(unsigned short u) {
    union { unsigned int i; float f; } v; v.i = ((unsigned int)u) << 16; return v.f;
}
__device__ inline unsigned short f2bf(float f) {
    __hip_bfloat16 h = __float2bfloat16(f);
    return *reinterpret_cast<unsigned short*>(&h);
}
// dtype-flexible load: f32i=1 -> float*, else bf16(ushort)*
__device__ inline float ldg(const void* p, size_t i, int f32i) {
    return f32i ? ((const float*)p)[i] : bf2f(((const ushort*)p)[i]);
}
__device__ inline float gelu_tanh(float x) {
    float u = 0.7978845608028654f * (x + 0.044715f * x * x * x);
    return 0.5f * x * (1.0f + tanhf(u));
}
__device__ inline void lds16(const void* g, void* l) {
    __builtin_amdgcn_global_load_lds((const __attribute__((address_space(1))) unsigned int*)g,
                                     (__attribute__((address_space(3))) unsigned int*)l, 16, 0, 0);
}

// ---------------- dtype detection ----------------
__global__ void detect_kernel(const ushort* __restrict__ xus, int* __restrict__ flag) {
    const int lane = threadIdx.x;  // 64
    int cnt = 0;
#pragma unroll
    for (int j = 0; j < 16; j++) {
        int p = lane * 16 + j;
        int eb = (xus[2 * p] >> 7) & 0xFF;
        cnt += (eb >= 100 && eb <= 140) ? 1 : 0;
    }
#pragma unroll
    for (int off = 32; off > 0; off >>= 1) cnt += __shfl_down(cnt, off, 64);
    if (lane == 0) flag[0] = (cnt < 512) ? 1 : 0;   // 1 = f32, 0 = bf16
}

// ---------------- zero the output ----------------
__global__ __launch_bounds__(256) void zero_kernel(void* __restrict__ out, const int* __restrict__ dflag) {
    const int f32i = *dflag;
    for (size_t i = (size_t)blockIdx.x * 256 + threadIdx.x; i < OUT_TOTAL; i += (size_t)gridDim.x * 256) {
        if (f32i) ((float*)out)[i] = 0.f; else ((ushort*)out)[i] = 0;
    }
}

// ---------------- zero f32 staging ----------------
__global__ __launch_bounds__(256) void zeroeo_kernel(float* __restrict__ p, size_t n) {
    for (size_t i = (size_t)blockIdx.x * 256 + threadIdx.x; i < n; i += (size_t)gridDim.x * 256)
        p[i] = 0.f;
}

// ---------------- x -> bf16 copy ----------------
__global__ __launch_bounds__(256) void convx_kernel(const void* __restrict__ x, const int* __restrict__ dflag,
                                                    ushort* __restrict__ xb) {
    const int f32i = *dflag;
    for (size_t i = (size_t)blockIdx.x * 256 + threadIdx.x; i < (size_t)S_TOKENS * DMODEL;
         i += (size_t)gridDim.x * 256)
        xb[i] = f32i ? f2bf(((const float*)x)[i]) : ((const ushort*)x)[i];
}

// ---------------- gating ----------------
__global__ __launch_bounds__(256) void gate_kernel(const void* __restrict__ x, const void* __restrict__ Wg,
                                                   const int* __restrict__ dflag,
                                                   float* __restrict__ gate1, float* __restrict__ gate2,
                                                   int* __restrict__ idx1, int* __restrict__ idx2,
                                                   float* __restrict__ bsum) {
    __shared__ float wgs[DMODEL * NEXP];   // 32 KB
    __shared__ float gsh[4][NEXP];
    const int t = threadIdx.x;
    const int f32i = *dflag;
    for (int i = t; i < DMODEL * NEXP; i += 256) wgs[i] = ldg(Wg, i, f32i);
    __syncthreads();
    const int wave = t >> 6, lane = t & 63;
    const int s = blockIdx.x * 4 + wave;
    float acc[NEXP];
#pragma unroll
    for (int e = 0; e < NEXP; e++) acc[e] = 0.f;
#pragma unroll
    for (int i = 0; i < 16; i++) {
        int d = i * 64 + lane;
        float xv = ldg(x, (size_t)s * DMODEL + d, f32i);
        const float* w = &wgs[d * NEXP];
#pragma unroll
        for (int e = 0; e < NEXP; e++) acc[e] += xv * w[e];
    }
#pragma unroll
    for (int off = 32; off > 0; off >>= 1)
#pragma unroll
        for (int e = 0; e < NEXP; e++) acc[e] += __shfl_down(acc[e], off, 64);
    if (lane == 0) {
        float mx = acc[0];
#pragma unroll
        for (int e = 1; e < NEXP; e++) mx = fmaxf(mx, acc[e]);
        float p[NEXP], se = 0.f;
#pragma unroll
        for (int e = 0; e < NEXP; e++) { p[e] = __expf(acc[e] - mx); se += p[e]; }
        float inv = 1.0f / se;
#pragma unroll
        for (int e = 0; e < NEXP; e++) p[e] *= inv;
        int i1 = 0; float g1v = p[0];
#pragma unroll
        for (int e = 1; e < NEXP; e++) if (p[e] > g1v) { g1v = p[e]; i1 = e; }
        int i2 = -1; float g2v = -1.0f;
#pragma unroll
        for (int e = 0; e < NEXP; e++) if (e != i1 && p[e] > g2v) { g2v = p[e]; i2 = e; }
        gate1[s] = g1v; gate2[s] = g2v; idx1[s] = i1; idx2[s] = i2;
#pragma unroll
        for (int e = 0; e < NEXP; e++) gsh[wave][e] = p[e];
    }
    __syncthreads();
    if (t < NEXP) bsum[blockIdx.x * NEXP + t] = gsh[0][t] + gsh[1][t] + gsh[2][t] + gsh[3][t];
}

// ---------------- parallel capacity scan ----------------
__global__ __launch_bounds__(256) void hist_kernel(const int* __restrict__ idx1, const int* __restrict__ idx2,
                                                   const float* __restrict__ bsum,
                                                   int* __restrict__ c1, int* __restrict__ c2,
                                                   float* __restrict__ msumB, int* __restrict__ rowmap) {
    const int b = blockIdx.x, t = threadIdx.x;
    const int w = t >> 6, lane = t & 63;
    __shared__ int sc1[4][NEXP], sc2[4][NEXP];
    __shared__ float sm[256];

    for (int i = b * 256 + t; i < NEXP * CAP; i += NCHUNK * 256) rowmap[i] = -1;

    const int s = b * 256 + w * 64 + lane;
    const int id1 = idx1[s], id2 = idx2[s];
#pragma unroll
    for (int e = 0; e < NEXP; e++) {
        unsigned long long m1 = __ballot(id1 == e);
        unsigned long long m2 = __ballot(id2 == e);
        if (lane == 0) { sc1[w][e] = __popcll(m1); sc2[w][e] = __popcll(m2); }
    }
    sm[t] = bsum[b * 512 + t] + bsum[b * 512 + 256 + t];
    __syncthreads();
    if (t < NEXP) {
        c1[b * NEXP + t] = sc1[0][t] + sc1[1][t] + sc1[2][t] + sc1[3][t];
        c2[b * NEXP + t] = sc2[0][t] + sc2[1][t] + sc2[2][t] + sc2[3][t];
        float ms = 0.f;
#pragma unroll
        for (int k = 0; k < 32; k++) ms += sm[t + NEXP * k];
        msumB[b * NEXP + t] = ms;
    }
}

__global__ void base_kernel(const int* __restrict__ c1, const int* __restrict__ c2,
                            const float* __restrict__ msumB, const int* __restrict__ dflag,
                            int* __restrict__ base1, int* __restrict__ base2, void* __restrict__ out) {
    const int lane = threadIdx.x;   // 64
    float contrib = 0.f;
    if (lane < NEXP) {
        int run = 0;
        for (int b = 0; b < NCHUNK; b++) { base1[b * NEXP + lane] = run; run += c1[b * NEXP + lane]; }
        const int count1 = run;
        int run2 = count1 < CAP ? count1 : CAP;   // used1 = min(count1, C)
        for (int b = 0; b < NCHUNK; b++) { base2[b * NEXP + lane] = run2; run2 += c2[b * NEXP + lane]; }
        float ms = 0.f;
        for (int b = 0; b < NCHUNK; b++) ms += msumB[b * NEXP + lane];
        contrib = (ms / (float)S_TOKENS) * ((float)count1 / (float)S_TOKENS);
    }
#pragma unroll
    for (int off = 4; off > 0; off >>= 1) contrib += __shfl_down(contrib, off, 64);
    if (lane == 0) {
        float L = 0.08f * contrib;   // 0.01 * mean(me*ce) * E*E
        if (*dflag) ((float*)out)[(size_t)S_TOKENS * DMODEL] = L;
        else        ((ushort*)out)[(size_t)S_TOKENS * DMODEL] = f2bf(L);
    }
}

__global__ __launch_bounds__(256) void place_kernel(const int* __restrict__ idx1, const int* __restrict__ idx2,
                                                    const int* __restrict__ base1, const int* __restrict__ base2,
                                                    int* __restrict__ p1i, int* __restrict__ p2i,
                                                    int* __restrict__ rowmap) {
    const int b = blockIdx.x, t = threadIdx.x;
    const int w = t >> 6, lane = t & 63;
    const unsigned long long below = (1ull << lane) - 1ull;
    __shared__ int wc1[4][NEXP], wc2[4][NEXP];
    const int s = b * 256 + w * 64 + lane;
    const int id1 = idx1[s], id2 = idx2[s];
    int r1 = 0, r2 = 0;
#pragma unroll
    for (int e = 0; e < NEXP; e++) {
        unsigned long long m1 = __ballot(id1 == e);
        if (id1 == e) r1 = __popcll(m1 & below);
        unsigned long long m2 = __ballot(id2 == e);
        if (id2 == e) r2 = __popcll(m2 & below);
        if (lane == 0) { wc1[w][e] = __popcll(m1); wc2[w][e] = __popcll(m2); }
    }
    __syncthreads();
    int off1 = 0, off2 = 0;
#pragma unroll
    for (int ww = 0; ww < 3; ww++) {
        if (ww < w) { off1 += wc1[ww][id1]; off2 += wc2[ww][id2]; }
    }
    const int pos1 = base1[b * NEXP + id1] + off1 + r1;
    if (pos1 < CAP) { p1i[s] = pos1; rowmap[id1 * CAP + pos1] = s; } else p1i[s] = -1;
    const int pos2 = base2[b * NEXP + id2] + off2 + r2;
    if (pos2 < CAP) { p2i[s] = pos2; rowmap[id2 * CAP + pos2] = s; } else p2i[s] = -1;
}

// ---------------- transpose + convert (expert-batched over blockIdx.z) ----------------
__global__ __launch_bounds__(256) void transpose_conv(const void* __restrict__ src, ushort* __restrict__ dst,
                                                      const int* __restrict__ dflag,
                                                      long srcBase, int srcStride, int dstStride,
                                                      long srcExpStride, long dstExpStride) {
    __shared__ ushort tile[64][68];
    const int f32i = *dflag;
    srcBase += (long)blockIdx.z * srcExpStride;
    dst     += (size_t)blockIdx.z * dstExpStride;
    const int c0 = blockIdx.x * 64, r0 = blockIdx.y * 64;
    const int tx = threadIdx.x & 15, ty = threadIdx.x >> 4;
#pragma unroll
    for (int k = 0; k < 4; k++) {
        int row = ty + 16 * k;
        size_t b = (size_t)srcBase + (size_t)(r0 + row) * srcStride + c0 + tx * 4;
#pragma unroll
        for (int j = 0; j < 4; j++) tile[row][tx * 4 + j] = f2bf(ldg(src, b + j, f32i));
    }
    __syncthreads();
#pragma unroll
    for (int k = 0; k < 4; k++) {
        int orow = ty + 16 * k;
        ushort4 v;
        v.x = tile[tx * 4 + 0][orow];
        v.y = tile[tx * 4 + 1][orow];
        v.z = tile[tx * 4 + 2][orow];
        v.w = tile[tx * 4 + 3][orow];
        *(ushort4*)(dst + (size_t)(c0 + orow) * dstStride + r0 + tx * 4) = v;
    }
}

// ---------------- GEMM1 (expert-batched over blockIdx.z) ----------------
template<int NC>
__global__ __launch_bounds__(256) void gemm1_kernel(const ushort* __restrict__ xb,
                                                    const int* __restrict__ rowmapBase,
                                                    const ushort* __restrict__ T,
                                                    const void* __restrict__ b1, long biasBase,
                                                    const int* __restrict__ dflag,
                                                    ushort* __restrict__ hout) {
    __shared__ ushort lA[128 * 32];
    __shared__ ushort lB[128 * 32];
    const int z = blockIdx.z;
    const int* rowmapE = rowmapBase + z * CAP;
    T    += (size_t)z * NC * DMODEL;
    hout += (size_t)z * CAP * NC;
    biasBase += (long)z * HFF;
    const int t = threadIdx.x;
    const int w = t >> 6, lane = t & 63;
    const int n0 = blockIdx.x * 128, m0 = blockIdx.y * 128;
    const int wr = w >> 1, wc = w & 1;
    const int l15 = lane & 15, quad = lane >> 4;
    const int swz = (lane >> 3) & 3;                 // staging source swizzle
    const int q2 = quad ^ ((l15 >> 1) & 3);          // read-side swizzle

    int arow[2];
#pragma unroll
    for (int it = 0; it < 2; it++) {
        int r = (it * 2048 + w * 512 + lane * 8) >> 5;
        int rm = rowmapE[m0 + r];
        arow[it] = rm < 0 ? 0 : rm;
    }

    f32x4 acc[4][4];
#pragma unroll
    for (int i = 0; i < 4; i++)
#pragma unroll
        for (int j = 0; j < 4; j++) acc[i][j] = (f32x4){0.f, 0.f, 0.f, 0.f};

    for (int k0 = 0; k0 < DMODEL; k0 += 32) {
        __syncthreads();
#pragma unroll
        for (int it = 0; it < 2; it++) {
            int f = it * 2048 + w * 512 + lane * 8;
            int r = f >> 5, kk = (f & 31) ^ (swz << 3);
            lds16(xb + (size_t)arow[it] * DMODEL + k0 + kk, &lA[it * 2048 + w * 512]);
            lds16(T + (size_t)(n0 + r) * DMODEL + k0 + kk, &lB[it * 2048 + w * 512]);
        }
        __syncthreads();
        bf16x8 af[4], bfr[4];
#pragma unroll
        for (int i = 0; i < 4; i++) af[i] = *(const bf16x8*)&lA[(wr * 64 + i * 16 + l15) * 32 + q2 * 8];
#pragma unroll
        for (int j = 0; j < 4; j++) bfr[j] = *(const bf16x8*)&lB[(wc * 64 + j * 16 + l15) * 32 + q2 * 8];
#pragma unroll
        for (int i = 0; i < 4; i++)
#pragma unroll
            for (int j = 0; j < 4; j++)
                acc[i][j] = __builtin_amdgcn_mfma_f32_16x16x32_bf16(af[i], bfr[j], acc[i][j], 0, 0, 0);
    }
    const int f32i = *dflag;
    float bv[4];
#pragma unroll
    for (int j = 0; j < 4; j++) bv[j] = ldg(b1, biasBase + n0 + wc * 64 + j * 16 + l15, f32i);
#pragma unroll
    for (int i = 0; i < 4; i++) {
        int row0 = m0 + wr * 64 + i * 16 + quad * 4;
#pragma unroll
        for (int j = 0; j < 4; j++) {
            int col = n0 + wc * 64 + j * 16 + l15;
#pragma unroll
            for (int r = 0; r < 4; r++)
                hout[(size_t)(row0 + r) * NC + col] = f2bf(gelu_tanh(acc[i][j][r] + bv[j]));
        }
    }
}

// ---------------- GEMM2 split-K (expert-batched): eo32 += h @ T2^T (f32 atomics) ----------------
// blockIdx.z = ze * (KC/KB) + zk
template<int KC, int KB>
__global__ __launch_bounds__(256) void gemm2s_kernel(const ushort* __restrict__ h,
                                                     const ushort* __restrict__ T2,
                                                     float* __restrict__ eo32) {
    __shared__ ushort lA[128 * 32];
    __shared__ ushort lB[128 * 32];
    constexpr int KSPLIT = KC / KB;
    const int zz = blockIdx.z;
    const int ze = zz / KSPLIT, zk = zz - ze * KSPLIT;
    h    += (size_t)ze * CAP * KC;
    T2   += (size_t)ze * DMODEL * KC;
    eo32 += (size_t)ze * CAP * DMODEL;
    const int t = threadIdx.x;
    const int w = t >> 6, lane = t & 63;
    const int n0 = blockIdx.x * 128, m0 = blockIdx.y * 128;
    const int kbeg = zk * KB;
    const int wr = w >> 1, wc = w & 1;
    const int l15 = lane & 15, quad = lane >> 4;
    const int swz = (lane >> 3) & 3;
    const int q2 = quad ^ ((l15 >> 1) & 3);

    f32x4 acc[4][4];
#pragma unroll
    for (int i = 0; i < 4; i++)
#pragma unroll
        for (int j = 0; j < 4; j++) acc[i][j] = (f32x4){0.f, 0.f, 0.f, 0.f};

    for (int k0 = kbeg; k0 < kbeg + KB; k0 += 32) {
        __syncthreads();
#pragma unroll
        for (int it = 0; it < 2; it++) {
            int f = it * 2048 + w * 512 + lane * 8;
            int r = f >> 5, kk = (f & 31) ^ (swz << 3);
            lds16(h  + (size_t)(m0 + r) * KC + k0 + kk, &lA[it * 2048 + w * 512]);
            lds16(T2 + (size_t)(n0 + r) * KC + k0 + kk, &lB[it * 2048 + w * 512]);
        }
        __syncthreads();
        bf16x8 af[4], bfr[4];
#pragma unroll
        for (int i = 0; i < 4; i++) af[i] = *(const bf16x8*)&lA[(wr * 64 + i * 16 + l15) * 32 + q2 * 8];
#pragma unroll
        for (int j = 0; j < 4; j++) bfr[j] = *(const bf16x8*)&lB[(wc * 64 + j * 16 + l15) * 32 + q2 * 8];
#pragma unroll
        for (int i = 0; i < 4; i++)
#pragma unroll
            for (int j = 0; j < 4; j++)
                acc[i][j] = __builtin_amdgcn_mfma_f32_16x16x32_bf16(af[i], bfr[j], acc[i][j], 0, 0, 0);
    }
#pragma unroll
    for (int i = 0; i < 4; i++) {
#pragma unroll
        for (int r = 0; r < 4; r++) {
            int row = m0 + wr * 64 + i * 16 + quad * 4 + r;
#pragma unroll
            for (int j = 0; j < 4; j++) {
                int col = n0 + wc * 64 + j * 16 + l15;
                atomicAdd(&eo32[(size_t)row * DMODEL + col], acc[i][j][r]);
            }
        }
    }
}

// ---------------- per-expert combine (scatter, sequential launches) ----------------
__global__ __launch_bounds__(256) void combine_kernel(const float* __restrict__ eo32, const void* __restrict__ b2,
                                                      long b2Base, const int* __restrict__ dflag,
                                                      const int* __restrict__ rowmapE, const int* __restrict__ idx1,
                                                      const int* __restrict__ p1i, const int* __restrict__ p2i,
                                                      const float* __restrict__ gate1, const float* __restrict__ gate2,
                                                      int expert, void* __restrict__ out) {
    const int t = threadIdx.x;
    const int f32i = *dflag;
    const int c0 = t * 4;
    float bv[4];
#pragma unroll
    for (int j = 0; j < 4; j++) bv[j] = ldg(b2, b2Base + c0 + j, f32i);
    for (int r = blockIdx.x; r < CAP; r += gridDim.x) {
        int s = rowmapE[r];
        if (s < 0) continue;
        float g1 = gate1[s], g2 = gate2[s];
        float k1 = (p1i[s] >= 0) ? 1.f : 0.f, k2 = (p2i[s] >= 0) ? 1.f : 0.f;
        float denom = g1 * k1 + g2 * k2 + 1e-9f;
        float wgt = ((idx1[s] == expert) ? g1 : g2) / denom;
        float4 ev = *(const float4*)&eo32[(size_t)r * DMODEL + c0];
        size_t oi = (size_t)s * DMODEL + c0;
        if (f32i) {
            float4* po = (float4*)((float*)out + oi);
            float4 ov = *po;
            ov.x += wgt * (ev.x + bv[0]); ov.y += wgt * (ev.y + bv[1]);
            ov.z += wgt * (ev.z + bv[2]); ov.w += wgt * (ev.w + bv[3]);
            *po = ov;
        } else {
            ushort* po = (ushort*)out + oi;
            ushort4 ov = *(ushort4*)po;
            ov.x = f2bf(bf2f(ov.x) + wgt * (ev.x + bv[0]));
            ov.y = f2bf(bf2f(ov.y) + wgt * (ev.y + bv[1]));
            ov.z = f2bf(bf2f(ov.z) + wgt * (ev.z + bv[2]));
            ov.w = f2bf(bf2f(ov.w) + wgt * (ev.w + bv[3]));
            *(ushort4*)po = ov;
        }
    }
}

// ---------------- all-expert gather combine: out[s] = w1*(eo[e1,p1]+b2[e1]) + w2*(eo[e2,p2]+b2[e2]) ----------------
__global__ __launch_bounds__(256) void combine_all_kernel(const float* __restrict__ eoall,
                                                          const void* __restrict__ b2,
                                                          const int* __restrict__ dflag,
                                                          const int* __restrict__ idx1, const int* __restrict__ idx2,
                                                          const int* __restrict__ p1i, const int* __restrict__ p2i,
                                                          const float* __restrict__ gate1, const float* __restrict__ gate2,
                                                          void* __restrict__ out) {
    const int s = blockIdx.x;
    const int t = threadIdx.x;
    const int c0 = t * 4;
    const int f32i = *dflag;
    const int e1 = idx1[s], e2 = idx2[s];
    const int p1 = p1i[s], p2 = p2i[s];
    const float g1 = gate1[s], g2 = gate2[s];
    const float k1 = (p1 >= 0) ? 1.f : 0.f, k2 = (p2 >= 0) ? 1.f : 0.f;
    const float denom = g1 * k1 + g2 * k2 + 1e-9f;
    const float w1 = g1 * k1 / denom, w2 = g2 * k2 / denom;
    float r0 = 0.f, r1 = 0.f, r2 = 0.f, r3 = 0.f;
    if (p1 >= 0) {
        const float4 ev = *(const float4*)&eoall[((size_t)e1 * CAP + p1) * DMODEL + c0];
        long bb = (long)e1 * DMODEL + c0;
        r0 += w1 * (ev.x + ldg(b2, bb + 0, f32i));
        r1 += w1 * (ev.y + ldg(b2, bb + 1, f32i));
        r2 += w1 * (ev.z + ldg(b2, bb + 2, f32i));
        r3 += w1 * (ev.w + ldg(b2, bb + 3, f32i));
    }
    if (p2 >= 0) {
        const float4 ev = *(const float4*)&eoall[((size_t)e2 * CAP + p2) * DMODEL + c0];
        long bb = (long)e2 * DMODEL + c0;
        r0 += w2 * (ev.x + ldg(b2, bb + 0, f32i));
        r1 += w2 * (ev.y + ldg(b2, bb + 1, f32i));
        r2 += w2 * (ev.z + ldg(b2, bb + 2, f32i));
        r3 += w2 * (ev.w + ldg(b2, bb + 3, f32i));
    }
    size_t oi = (size_t)s * DMODEL + c0;
    if (f32i) {
        float4 ov; ov.x = r0; ov.y = r1; ov.z = r2; ov.w = r3;
        *(float4*)((float*)out + oi) = ov;
    } else {
        ushort4 ov; ov.x = f2bf(r0); ov.y = f2bf(r1); ov.z = f2bf(r2); ov.w = f2bf(r3);
        *(ushort4*)((ushort*)out + oi) = ov;
    }
}

// ---------------- shared prologue ----------------
struct WsPtrs {
    int *flag, *rowmap, *idx1, *idx2, *p1i, *p2i, *c1, *c2, *base1, *base2;
    float *gate1, *gate2, *bsum, *msumB;
    ushort* xb;
};
static WsPtrs ws_ptrs(char* ws) {
    WsPtrs p;
    p.flag   = (int*)ws;
    p.rowmap = (int*)(ws + 256);
    p.gate1  = (float*)(ws + 82176);
    p.gate2  = (float*)(ws + 147712);
    p.idx1   = (int*)(ws + 213248);
    p.idx2   = (int*)(ws + 278784);
    p.p1i    = (int*)(ws + 344320);
    p.p2i    = (int*)(ws + 409856);
    p.bsum   = (float*)(ws + 475392);
    p.c1     = (int*)(ws + 606464);
    p.c2     = (int*)(ws + 608512);
    p.msumB  = (float*)(ws + 610560);
    p.base1  = (int*)(ws + 612608);
    p.base2  = (int*)(ws + 614656);
    p.xb     = (ushort*)(ws + 655360);   // 33,554,432 B
    return p;
}
static void prologue(const void* x, const void* Wg, const WsPtrs& p, void* out, hipStream_t stream,
                     bool zeroOut) {
    detect_kernel<<<dim3(1), 64, 0, stream>>>((const ushort*)x, p.flag);
    if (zeroOut) zero_kernel<<<dim3(16384), 256, 0, stream>>>(out, p.flag);
    convx_kernel<<<dim3(8192), 256, 0, stream>>>(x, p.flag, p.xb);
    gate_kernel<<<dim3(S_TOKENS / 4), 256, 0, stream>>>(x, Wg, p.flag, p.gate1, p.gate2, p.idx1, p.idx2, p.bsum);
    hist_kernel<<<dim3(NCHUNK), 256, 0, stream>>>(p.idx1, p.idx2, p.bsum, p.c1, p.c2, p.msumB, p.rowmap);
    base_kernel<<<dim3(1), 64, 0, stream>>>(p.c1, p.c2, p.msumB, p.flag, p.base1, p.base2, out);
    place_kernel<<<dim3(NCHUNK), 256, 0, stream>>>(p.idx1, p.idx2, p.base1, p.base2, p.p1i, p.p2i, p.rowmap);
}

// ---------------- expert-batched design ----------------
// EB experts per launch; fullCombine => eo32 for all 8 experts + one gather combine.
template<int EB>
static void run_moe_batched(const void* x, const void* Wg, const void* W1, const void* b1,
                            const void* W2, const void* b2, void* out, char* ws, hipStream_t stream,
                            bool fullCombine) {
    WsPtrs p = ws_ptrs(ws);
    char* cur = ws + 655360 + 33554432;
    ushort* h = (ushort*)cur;  cur += (size_t)EB * CAP * HFF * 2;      // EB * 20,971,520
    ushort* T = (ushort*)cur;  cur += (size_t)EB * HFF * DMODEL * 2;   // EB * 8,388,608
    float* eo = (float*)cur;   // fullCombine: 8 * CAP*D f32; else EB * CAP*D f32

    prologue(x, Wg, p, out, stream, !fullCombine);
    for (int b = 0; b < NEXP / EB; b++) {
        const int e0 = b * EB;
        float* eoS = fullCombine ? eo + (size_t)e0 * CAP * DMODEL : eo;
        transpose_conv<<<dim3(HFF / 64, DMODEL / 64, EB), 256, 0, stream>>>(
            W1, T, p.flag, (long)e0 * DMODEL * HFF, HFF, DMODEL,
            (long)DMODEL * HFF, (long)HFF * DMODEL);                     // T[z] = W1[e0+z]^T [4096][1024]
        gemm1_kernel<HFF><<<dim3(HFF / 128, CAP / 128, EB), 256, 0, stream>>>(
            p.xb, p.rowmap + e0 * CAP, T, b1, (long)e0 * HFF, p.flag, h);
        zeroeo_kernel<<<dim3(4096), 256, 0, stream>>>(eoS, (size_t)EB * CAP * DMODEL);
        transpose_conv<<<dim3(DMODEL / 64, HFF / 64, EB), 256, 0, stream>>>(
            W2, T, p.flag, (long)e0 * HFF * DMODEL, DMODEL, HFF,
            (long)HFF * DMODEL, (long)DMODEL * HFF);                     // T[z] = W2[e0+z]^T [1024][4096]
        gemm2s_kernel<HFF, 1024><<<dim3(DMODEL / 128, CAP / 128, 4 * EB), 256, 0, stream>>>(h, T, eoS);
        if (!fullCombine) {
            for (int q = 0; q < EB; q++)
                combine_kernel<<<dim3(1280), 256, 0, stream>>>(
                    eo + (size_t)q * CAP * DMODEL, b2, (long)(e0 + q) * DMODEL, p.flag,
                    p.rowmap + (e0 + q) * CAP, p.idx1, p.p1i, p.p2i, p.gate1, p.gate2, e0 + q, out);
        }
    }
    if (fullCombine)
        combine_all_kernel<<<dim3(S_TOKENS), 256, 0, stream>>>(
            eo, b2, p.flag, p.idx1, p.idx2, p.p1i, p.p2i, p.gate1, p.gate2, out);
}

// ---------------- design A: full-H per expert (ws >= ~74.1 MB) ----------------
static void run_moe_a(const void* x, const void* Wg, const void* W1, const void* b1,
                      const void* W2, const void* b2, void* out, char* ws, hipStream_t stream) {
    WsPtrs p = ws_ptrs(ws);
    ushort* h    = (ushort*)(ws + 655360 + 33554432);            // 20,971,520
    ushort* T    = (ushort*)(ws + 655360 + 33554432 + 20971520); // 8,388,608
    float*  eo32 = (float*)(ws + 655360 + 33554432 + 20971520 + 8388608); // 10,485,760

    prologue(x, Wg, p, out, stream, true);
    for (int e = 0; e < NEXP; e++) {
        transpose_conv<<<dim3(HFF / 64, DMODEL / 64), 256, 0, stream>>>(
            W1, T, p.flag, (long)e * DMODEL * HFF, HFF, DMODEL, 0, 0);
        gemm1_kernel<HFF><<<dim3(HFF / 128, CAP / 128), 256, 0, stream>>>(
            p.xb, p.rowmap + e * CAP, T, b1, (long)e * HFF, p.flag, h);
        zeroeo_kernel<<<dim3(2048), 256, 0, stream>>>(eo32, (size_t)CAP * DMODEL);
        transpose_conv<<<dim3(DMODEL / 64, HFF / 64), 256, 0, stream>>>(
            W2, T, p.flag, (long)e * HFF * DMODEL, DMODEL, HFF, 0, 0);
        gemm2s_kernel<HFF, 512><<<dim3(DMODEL / 128, CAP / 128, HFF / 512), 256, 0, stream>>>(h, T, eo32);
        combine_kernel<<<dim3(1280), 256, 0, stream>>>(
            eo32, b2, (long)e * DMODEL, p.flag, p.rowmap + e * CAP,
            p.idx1, p.p1i, p.p2i, p.gate1, p.gate2, e, out);
    }
}

// ---------------- design B: H chunked at 2048 (ws >= ~59.4 MB) ----------------
static void run_moe_b(const void* x, const void* Wg, const void* W1, const void* b1,
                      const void* W2, const void* b2, void* out, char* ws, hipStream_t stream) {
    WsPtrs p = ws_ptrs(ws);
    const int HC = 2048;
    ushort* h    = (ushort*)(ws + 655360 + 33554432);            // 10,485,760
    ushort* T    = (ushort*)(ws + 655360 + 33554432 + 10485760); // 4,194,304
    float*  eo32 = (float*)(ws + 655360 + 33554432 + 10485760 + 4194304); // 10,485,760

    prologue(x, Wg, p, out, stream, true);
    for (int e = 0; e < NEXP; e++) {
        zeroeo_kernel<<<dim3(2048), 256, 0, stream>>>(eo32, (size_t)CAP * DMODEL);
        for (int c = 0; c < HFF / HC; c++) {
            const long hoff = (long)c * HC;
            transpose_conv<<<dim3(HC / 64, DMODEL / 64), 256, 0, stream>>>(
                W1, T, p.flag, (long)e * DMODEL * HFF + hoff, HFF, DMODEL, 0, 0);
            gemm1_kernel<HC><<<dim3(HC / 128, CAP / 128), 256, 0, stream>>>(
                p.xb, p.rowmap + e * CAP, T, b1, (long)e * HFF + hoff, p.flag, h);
            transpose_conv<<<dim3(DMODEL / 64, HC / 64), 256, 0, stream>>>(
                W2, T, p.flag, (long)e * HFF * DMODEL + hoff * DMODEL, DMODEL, HC, 0, 0);
            gemm2s_kernel<2048, 1024><<<dim3(DMODEL / 128, CAP / 128, 2), 256, 0, stream>>>(h, T, eo32);
        }
        combine_kernel<<<dim3(1280), 256, 0, stream>>>(
            eo32, b2, (long)e * DMODEL, p.flag, p.rowmap + e * CAP,
            p.idx1, p.p1i, p.p2i, p.gate1, p.gate2, e, out);
    }
}

// ---------------- launcher ----------------
extern "C" void kernel_launch(void* const* d_in, const int* in_sizes, int n_in,
                              void* d_out, int out_size, void* d_ws, size_t ws_size,
                              hipStream_t stream) {
    const void* x  = d_in[0];
    const void* Wg = d_in[1];
    const void* W1 = d_in[2];
    const void* b1 = d_in[3];
    const void* W2 = d_in[4];
    const void* b2 = d_in[5];
    char* ws = (char*)d_ws;

    // footprints: EB=4 full: 34.2+83.9+33.6+83.9 = 235.6 MB; EB=2 full: 176.9 MB;
    //             EB=2 pair: 113.9 MB; A: 74.1 MB; B: 59.4 MB
    if (ws_size >= 236000000ull)      run_moe_batched<4>(x, Wg, W1, b1, W2, b2, d_out, ws, stream, true);
    else if (ws_size >= 177000000ull) run_moe_batched<2>(x, Wg, W1, b1, W2, b2, d_out, ws, stream, true);
    else if (ws_size >= 114500000ull) run_moe_batched<2>(x, Wg, W1, b1, W2, b2, d_out, ws, stream, false);
    else if (ws_size >= 74200000ull)  run_moe_a(x, Wg, W1, b1, W2, b2, d_out, ws, stream);
    else                              run_moe_b(x, Wg, W1, b1, W2, b2, d_out, ws, stream);
}

// Round 5
// 1141.722 us; speedup vs baseline: 1.6281x; 1.0486x over previous
//
#include <hip/hip_runtime.h>
#include <hip/hip_bf16.h>

// ---------------- problem constants ----------------
#define S_TOKENS 16384   // B*N
#define DMODEL   1024
#define NEXP     8
#define HFF      4096
#define CAP      2560    // int(S*1.25/E)
#define OUT_TOTAL (S_TOKENS * DMODEL + 1)
#define NCHUNK   64      // scan chunks (256 tokens each)

typedef __attribute__((ext_vector_type(8))) short bf16x8;
typedef __attribute__((ext_vector_type(4))) float f32x4;

__device__ inline float bf2f(unsigned short u) {
    union { unsigned int i; float f; } v; v.i = ((unsigned int)u) << 16; return v.f;
}
__device__ inline unsigned short f2bf(float f) {
    __hip_bfloat16 h = __float2bfloat16(f);
    return *reinterpret_cast<unsigned short*>(&h);
}
// dtype-flexible load: f32i=1 -> float*, else bf16(ushort)*
__device__ inline float ldg(const void* p, size_t i, int f32i) {
    return f32i ? ((const float*)p)[i] : bf2f(((const ushort*)p)[i]);
}
__device__ inline float gelu_tanh(float x) {
    float u = 0.7978845608028654f * (x + 0.044715f * x * x * x);
    return 0.5f * x * (1.0f + tanhf(u));
}
__device__ inline void lds16(const void* g, void* l) {
    __builtin_amdgcn_global_load_lds((const __attribute__((address_space(1))) unsigned int*)g,
                                     (__attribute__((address_space(3))) unsigned int*)l, 16, 0, 0);
}

// ---------------- dtype detection ----------------
__global__ void detect_kernel(const ushort* __restrict__ xus, int* __restrict__ flag) {
    const int lane = threadIdx.x;  // 64
    int cnt = 0;
#pragma unroll
    for (int j = 0; j < 16; j++) {
        int p = lane * 16 + j;
        int eb = (xus[2 * p] >> 7) & 0xFF;
        cnt += (eb >= 100 && eb <= 140) ? 1 : 0;
    }
#pragma unroll
    for (int off = 32; off > 0; off >>= 1) cnt += __shfl_down(cnt, off, 64);
    if (lane == 0) flag[0] = (cnt < 512) ? 1 : 0;   // 1 = f32, 0 = bf16
}

// ---------------- zero the output ----------------
__global__ __launch_bounds__(256) void zero_kernel(void* __restrict__ out, const int* __restrict__ dflag) {
    const int f32i = *dflag;
    for (size_t i = (size_t)blockIdx.x * 256 + threadIdx.x; i < OUT_TOTAL; i += (size_t)gridDim.x * 256) {
        if (f32i) ((float*)out)[i] = 0.f; else ((ushort*)out)[i] = 0;
    }
}

// ---------------- zero f32 staging ----------------
__global__ __launch_bounds__(256) void zeroeo_kernel(float* __restrict__ p, size_t n) {
    for (size_t i = (size_t)blockIdx.x * 256 + threadIdx.x; i < n; i += (size_t)gridDim.x * 256)
        p[i] = 0.f;
}

// ---------------- x -> bf16 copy ----------------
__global__ __launch_bounds__(256) void convx_kernel(const void* __restrict__ x, const int* __restrict__ dflag,
                                                    ushort* __restrict__ xb) {
    const int f32i = *dflag;
    for (size_t i = (size_t)blockIdx.x * 256 + threadIdx.x; i < (size_t)S_TOKENS * DMODEL;
         i += (size_t)gridDim.x * 256)
        xb[i] = f32i ? f2bf(((const float*)x)[i]) : ((const ushort*)x)[i];
}

// ---------------- gating ----------------
__global__ __launch_bounds__(256) void gate_kernel(const void* __restrict__ x, const void* __restrict__ Wg,
                                                   const int* __restrict__ dflag,
                                                   float* __restrict__ gate1, float* __restrict__ gate2,
                                                   int* __restrict__ idx1, int* __restrict__ idx2,
                                                   float* __restrict__ bsum) {
    __shared__ float wgs[DMODEL * NEXP];   // 32 KB
    __shared__ float gsh[4][NEXP];
    const int t = threadIdx.x;
    const int f32i = *dflag;
    for (int i = t; i < DMODEL * NEXP; i += 256) wgs[i] = ldg(Wg, i, f32i);
    __syncthreads();
    const int wave = t >> 6, lane = t & 63;
    const int s = blockIdx.x * 4 + wave;
    float acc[NEXP];
#pragma unroll
    for (int e = 0; e < NEXP; e++) acc[e] = 0.f;
#pragma unroll
    for (int i = 0; i < 16; i++) {
        int d = i * 64 + lane;
        float xv = ldg(x, (size_t)s * DMODEL + d, f32i);
        const float* w = &wgs[d * NEXP];
#pragma unroll
        for (int e = 0; e < NEXP; e++) acc[e] += xv * w[e];
    }
#pragma unroll
    for (int off = 32; off > 0; off >>= 1)
#pragma unroll
        for (int e = 0; e < NEXP; e++) acc[e] += __shfl_down(acc[e], off, 64);
    if (lane == 0) {
        float mx = acc[0];
#pragma unroll
        for (int e = 1; e < NEXP; e++) mx = fmaxf(mx, acc[e]);
        float p[NEXP], se = 0.f;
#pragma unroll
        for (int e = 0; e < NEXP; e++) { p[e] = __expf(acc[e] - mx); se += p[e]; }
        float inv = 1.0f / se;
#pragma unroll
        for (int e = 0; e < NEXP; e++) p[e] *= inv;
        int i1 = 0; float g1v = p[0];
#pragma unroll
        for (int e = 1; e < NEXP; e++) if (p[e] > g1v) { g1v = p[e]; i1 = e; }
        int i2 = -1; float g2v = -1.0f;
#pragma unroll
        for (int e = 0; e < NEXP; e++) if (e != i1 && p[e] > g2v) { g2v = p[e]; i2 = e; }
        gate1[s] = g1v; gate2[s] = g2v; idx1[s] = i1; idx2[s] = i2;
#pragma unroll
        for (int e = 0; e < NEXP; e++) gsh[wave][e] = p[e];
    }
    __syncthreads();
    if (t < NEXP) bsum[blockIdx.x * NEXP + t] = gsh[0][t] + gsh[1][t] + gsh[2][t] + gsh[3][t];
}

// ---------------- parallel capacity scan ----------------
__global__ __launch_bounds__(256) void hist_kernel(const int* __restrict__ idx1, const int* __restrict__ idx2,
                                                   const float* __restrict__ bsum,
                                                   int* __restrict__ c1, int* __restrict__ c2,
                                                   float* __restrict__ msumB, int* __restrict__ rowmap) {
    const int b = blockIdx.x, t = threadIdx.x;
    const int w = t >> 6, lane = t & 63;
    __shared__ int sc1[4][NEXP], sc2[4][NEXP];
    __shared__ float sm[256];

    for (int i = b * 256 + t; i < NEXP * CAP; i += NCHUNK * 256) rowmap[i] = -1;

    const int s = b * 256 + w * 64 + lane;
    const int id1 = idx1[s], id2 = idx2[s];
#pragma unroll
    for (int e = 0; e < NEXP; e++) {
        unsigned long long m1 = __ballot(id1 == e);
        unsigned long long m2 = __ballot(id2 == e);
        if (lane == 0) { sc1[w][e] = __popcll(m1); sc2[w][e] = __popcll(m2); }
    }
    sm[t] = bsum[b * 512 + t] + bsum[b * 512 + 256 + t];
    __syncthreads();
    if (t < NEXP) {
        c1[b * NEXP + t] = sc1[0][t] + sc1[1][t] + sc1[2][t] + sc1[3][t];
        c2[b * NEXP + t] = sc2[0][t] + sc2[1][t] + sc2[2][t] + sc2[3][t];
        float ms = 0.f;
#pragma unroll
        for (int k = 0; k < 32; k++) ms += sm[t + NEXP * k];
        msumB[b * NEXP + t] = ms;
    }
}

__global__ void base_kernel(const int* __restrict__ c1, const int* __restrict__ c2,
                            const float* __restrict__ msumB, const int* __restrict__ dflag,
                            int* __restrict__ base1, int* __restrict__ base2, void* __restrict__ out) {
    const int lane = threadIdx.x;   // 64
    float contrib = 0.f;
    if (lane < NEXP) {
        int run = 0;
        for (int b = 0; b < NCHUNK; b++) { base1[b * NEXP + lane] = run; run += c1[b * NEXP + lane]; }
        const int count1 = run;
        int run2 = count1 < CAP ? count1 : CAP;   // used1 = min(count1, C)
        for (int b = 0; b < NCHUNK; b++) { base2[b * NEXP + lane] = run2; run2 += c2[b * NEXP + lane]; }
        float ms = 0.f;
        for (int b = 0; b < NCHUNK; b++) ms += msumB[b * NEXP + lane];
        contrib = (ms / (float)S_TOKENS) * ((float)count1 / (float)S_TOKENS);
    }
#pragma unroll
    for (int off = 4; off > 0; off >>= 1) contrib += __shfl_down(contrib, off, 64);
    if (lane == 0) {
        float L = 0.08f * contrib;   // 0.01 * mean(me*ce) * E*E
        if (*dflag) ((float*)out)[(size_t)S_TOKENS * DMODEL] = L;
        else        ((ushort*)out)[(size_t)S_TOKENS * DMODEL] = f2bf(L);
    }
}

__global__ __launch_bounds__(256) void place_kernel(const int* __restrict__ idx1, const int* __restrict__ idx2,
                                                    const int* __restrict__ base1, const int* __restrict__ base2,
                                                    int* __restrict__ p1i, int* __restrict__ p2i,
                                                    int* __restrict__ rowmap) {
    const int b = blockIdx.x, t = threadIdx.x;
    const int w = t >> 6, lane = t & 63;
    const unsigned long long below = (1ull << lane) - 1ull;
    __shared__ int wc1[4][NEXP], wc2[4][NEXP];
    const int s = b * 256 + w * 64 + lane;
    const int id1 = idx1[s], id2 = idx2[s];
    int r1 = 0, r2 = 0;
#pragma unroll
    for (int e = 0; e < NEXP; e++) {
        unsigned long long m1 = __ballot(id1 == e);
        if (id1 == e) r1 = __popcll(m1 & below);
        unsigned long long m2 = __ballot(id2 == e);
        if (id2 == e) r2 = __popcll(m2 & below);
        if (lane == 0) { wc1[w][e] = __popcll(m1); wc2[w][e] = __popcll(m2); }
    }
    __syncthreads();
    int off1 = 0, off2 = 0;
#pragma unroll
    for (int ww = 0; ww < 3; ww++) {
        if (ww < w) { off1 += wc1[ww][id1]; off2 += wc2[ww][id2]; }
    }
    const int pos1 = base1[b * NEXP + id1] + off1 + r1;
    if (pos1 < CAP) { p1i[s] = pos1; rowmap[id1 * CAP + pos1] = s; } else p1i[s] = -1;
    const int pos2 = base2[b * NEXP + id2] + off2 + r2;
    if (pos2 < CAP) { p2i[s] = pos2; rowmap[id2 * CAP + pos2] = s; } else p2i[s] = -1;
}

// ---------------- transpose + convert (expert-batched over blockIdx.z) ----------------
__global__ __launch_bounds__(256) void transpose_conv(const void* __restrict__ src, ushort* __restrict__ dst,
                                                      const int* __restrict__ dflag,
                                                      long srcBase, int srcStride, int dstStride,
                                                      long srcExpStride, long dstExpStride) {
    __shared__ ushort tile[64][68];
    const int f32i = *dflag;
    srcBase += (long)blockIdx.z * srcExpStride;
    dst     += (size_t)blockIdx.z * dstExpStride;
    const int c0 = blockIdx.x * 64, r0 = blockIdx.y * 64;
    const int tx = threadIdx.x & 15, ty = threadIdx.x >> 4;
#pragma unroll
    for (int k = 0; k < 4; k++) {
        int row = ty + 16 * k;
        size_t b = (size_t)srcBase + (size_t)(r0 + row) * srcStride + c0 + tx * 4;
#pragma unroll
        for (int j = 0; j < 4; j++) tile[row][tx * 4 + j] = f2bf(ldg(src, b + j, f32i));
    }
    __syncthreads();
#pragma unroll
    for (int k = 0; k < 4; k++) {
        int orow = ty + 16 * k;
        ushort4 v;
        v.x = tile[tx * 4 + 0][orow];
        v.y = tile[tx * 4 + 1][orow];
        v.z = tile[tx * 4 + 2][orow];
        v.w = tile[tx * 4 + 3][orow];
        *(ushort4*)(dst + (size_t)(c0 + orow) * dstStride + r0 + tx * 4) = v;
    }
}

// ---------------- GEMM1 (expert-batched over blockIdx.z) ----------------
template<int NC>
__global__ __launch_bounds__(256) void gemm1_kernel(const ushort* __restrict__ xb,
                                                    const int* __restrict__ rowmapBase,
                                                    const ushort* __restrict__ T,
                                                    const void* __restrict__ b1, long biasBase,
                                                    const int* __restrict__ dflag,
                                                    ushort* __restrict__ hout) {
    __shared__ ushort lA[128 * 32];
    __shared__ ushort lB[128 * 32];
    const int z = blockIdx.z;
    const int* rowmapE = rowmapBase + z * CAP;
    T    += (size_t)z * NC * DMODEL;
    hout += (size_t)z * CAP * NC;
    biasBase += (long)z * HFF;
    const int t = threadIdx.x;
    const int w = t >> 6, lane = t & 63;
    const int n0 = blockIdx.x * 128, m0 = blockIdx.y * 128;
    const int wr = w >> 1, wc = w & 1;
    const int l15 = lane & 15, quad = lane >> 4;
    const int swz = (lane >> 3) & 3;                 // staging source swizzle
    const int q2 = quad ^ ((l15 >> 1) & 3);          // read-side swizzle

    int arow[2];
#pragma unroll
    for (int it = 0; it < 2; it++) {
        int r = (it * 2048 + w * 512 + lane * 8) >> 5;
        int rm = rowmapE[m0 + r];
        arow[it] = rm < 0 ? 0 : rm;
    }

    f32x4 acc[4][4];
#pragma unroll
    for (int i = 0; i < 4; i++)
#pragma unroll
        for (int j = 0; j < 4; j++) acc[i][j] = (f32x4){0.f, 0.f, 0.f, 0.f};

    for (int k0 = 0; k0 < DMODEL; k0 += 32) {
        __syncthreads();
#pragma unroll
        for (int it = 0; it < 2; it++) {
            int f = it * 2048 + w * 512 + lane * 8;
            int r = f >> 5, kk = (f & 31) ^ (swz << 3);
            lds16(xb + (size_t)arow[it] * DMODEL + k0 + kk, &lA[it * 2048 + w * 512]);
            lds16(T + (size_t)(n0 + r) * DMODEL + k0 + kk, &lB[it * 2048 + w * 512]);
        }
        __syncthreads();
        bf16x8 af[4], bfr[4];
#pragma unroll
        for (int i = 0; i < 4; i++) af[i] = *(const bf16x8*)&lA[(wr * 64 + i * 16 + l15) * 32 + q2 * 8];
#pragma unroll
        for (int j = 0; j < 4; j++) bfr[j] = *(const bf16x8*)&lB[(wc * 64 + j * 16 + l15) * 32 + q2 * 8];
#pragma unroll
        for (int i = 0; i < 4; i++)
#pragma unroll
            for (int j = 0; j < 4; j++)
                acc[i][j] = __builtin_amdgcn_mfma_f32_16x16x32_bf16(af[i], bfr[j], acc[i][j], 0, 0, 0);
    }
    const int f32i = *dflag;
    float bv[4];
#pragma unroll
    for (int j = 0; j < 4; j++) bv[j] = ldg(b1, biasBase + n0 + wc * 64 + j * 16 + l15, f32i);
#pragma unroll
    for (int i = 0; i < 4; i++) {
        int row0 = m0 + wr * 64 + i * 16 + quad * 4;
#pragma unroll
        for (int j = 0; j < 4; j++) {
            int col = n0 + wc * 64 + j * 16 + l15;
#pragma unroll
            for (int r = 0; r < 4; r++)
                hout[(size_t)(row0 + r) * NC + col] = f2bf(gelu_tanh(acc[i][j][r] + bv[j]));
        }
    }
}

// ---------------- GEMM2 full-K (expert-batched, output-stationary, NO atomics) ----------------
// eo32[ze][row][col] = h[ze] @ T2[ze]^T ; plain f32 stores, no zero-init needed.
template<int KC>
__global__ __launch_bounds__(256) void gemm2f_kernel(const ushort* __restrict__ h,
                                                     const ushort* __restrict__ T2,
                                                     float* __restrict__ eo32) {
    __shared__ ushort lA[128 * 32];
    __shared__ ushort lB[128 * 32];
    const int ze = blockIdx.z;
    h    += (size_t)ze * CAP * KC;
    T2   += (size_t)ze * DMODEL * KC;
    eo32 += (size_t)ze * CAP * DMODEL;
    const int t = threadIdx.x;
    const int w = t >> 6, lane = t & 63;
    const int n0 = blockIdx.x * 128, m0 = blockIdx.y * 128;
    const int wr = w >> 1, wc = w & 1;
    const int l15 = lane & 15, quad = lane >> 4;
    const int swz = (lane >> 3) & 3;
    const int q2 = quad ^ ((l15 >> 1) & 3);

    f32x4 acc[4][4];
#pragma unroll
    for (int i = 0; i < 4; i++)
#pragma unroll
        for (int j = 0; j < 4; j++) acc[i][j] = (f32x4){0.f, 0.f, 0.f, 0.f};

    for (int k0 = 0; k0 < KC; k0 += 32) {
        __syncthreads();
#pragma unroll
        for (int it = 0; it < 2; it++) {
            int f = it * 2048 + w * 512 + lane * 8;
            int r = f >> 5, kk = (f & 31) ^ (swz << 3);
            lds16(h  + (size_t)(m0 + r) * KC + k0 + kk, &lA[it * 2048 + w * 512]);
            lds16(T2 + (size_t)(n0 + r) * KC + k0 + kk, &lB[it * 2048 + w * 512]);
        }
        __syncthreads();
        bf16x8 af[4], bfr[4];
#pragma unroll
        for (int i = 0; i < 4; i++) af[i] = *(const bf16x8*)&lA[(wr * 64 + i * 16 + l15) * 32 + q2 * 8];
#pragma unroll
        for (int j = 0; j < 4; j++) bfr[j] = *(const bf16x8*)&lB[(wc * 64 + j * 16 + l15) * 32 + q2 * 8];
#pragma unroll
        for (int i = 0; i < 4; i++)
#pragma unroll
            for (int j = 0; j < 4; j++)
                acc[i][j] = __builtin_amdgcn_mfma_f32_16x16x32_bf16(af[i], bfr[j], acc[i][j], 0, 0, 0);
    }
#pragma unroll
    for (int i = 0; i < 4; i++) {
#pragma unroll
        for (int r = 0; r < 4; r++) {
            int row = m0 + wr * 64 + i * 16 + quad * 4 + r;
#pragma unroll
            for (int j = 0; j < 4; j++) {
                int col = n0 + wc * 64 + j * 16 + l15;
                eo32[(size_t)row * DMODEL + col] = acc[i][j][r];
            }
        }
    }
}

// ---------------- GEMM2 split-K (legacy tiers): eo32 += h @ T2^T (f32 atomics) ----------------
template<int KC, int KB>
__global__ __launch_bounds__(256) void gemm2s_kernel(const ushort* __restrict__ h,
                                                     const ushort* __restrict__ T2,
                                                     float* __restrict__ eo32) {
    __shared__ ushort lA[128 * 32];
    __shared__ ushort lB[128 * 32];
    constexpr int KSPLIT = KC / KB;
    const int zz = blockIdx.z;
    const int ze = zz / KSPLIT, zk = zz - ze * KSPLIT;
    h    += (size_t)ze * CAP * KC;
    T2   += (size_t)ze * DMODEL * KC;
    eo32 += (size_t)ze * CAP * DMODEL;
    const int t = threadIdx.x;
    const int w = t >> 6, lane = t & 63;
    const int n0 = blockIdx.x * 128, m0 = blockIdx.y * 128;
    const int kbeg = zk * KB;
    const int wr = w >> 1, wc = w & 1;
    const int l15 = lane & 15, quad = lane >> 4;
    const int swz = (lane >> 3) & 3;
    const int q2 = quad ^ ((l15 >> 1) & 3);

    f32x4 acc[4][4];
#pragma unroll
    for (int i = 0; i < 4; i++)
#pragma unroll
        for (int j = 0; j < 4; j++) acc[i][j] = (f32x4){0.f, 0.f, 0.f, 0.f};

    for (int k0 = kbeg; k0 < kbeg + KB; k0 += 32) {
        __syncthreads();
#pragma unroll
        for (int it = 0; it < 2; it++) {
            int f = it * 2048 + w * 512 + lane * 8;
            int r = f >> 5, kk = (f & 31) ^ (swz << 3);
            lds16(h  + (size_t)(m0 + r) * KC + k0 + kk, &lA[it * 2048 + w * 512]);
            lds16(T2 + (size_t)(n0 + r) * KC + k0 + kk, &lB[it * 2048 + w * 512]);
        }
        __syncthreads();
        bf16x8 af[4], bfr[4];
#pragma unroll
        for (int i = 0; i < 4; i++) af[i] = *(const bf16x8*)&lA[(wr * 64 + i * 16 + l15) * 32 + q2 * 8];
#pragma unroll
        for (int j = 0; j < 4; j++) bfr[j] = *(const bf16x8*)&lB[(wc * 64 + j * 16 + l15) * 32 + q2 * 8];
#pragma unroll
        for (int i = 0; i < 4; i++)
#pragma unroll
            for (int j = 0; j < 4; j++)
                acc[i][j] = __builtin_amdgcn_mfma_f32_16x16x32_bf16(af[i], bfr[j], acc[i][j], 0, 0, 0);
    }
#pragma unroll
    for (int i = 0; i < 4; i++) {
#pragma unroll
        for (int r = 0; r < 4; r++) {
            int row = m0 + wr * 64 + i * 16 + quad * 4 + r;
#pragma unroll
            for (int j = 0; j < 4; j++) {
                int col = n0 + wc * 64 + j * 16 + l15;
                atomicAdd(&eo32[(size_t)row * DMODEL + col], acc[i][j][r]);
            }
        }
    }
}

// ---------------- per-expert combine (scatter, sequential launches) ----------------
__global__ __launch_bounds__(256) void combine_kernel(const float* __restrict__ eo32, const void* __restrict__ b2,
                                                      long b2Base, const int* __restrict__ dflag,
                                                      const int* __restrict__ rowmapE, const int* __restrict__ idx1,
                                                      const int* __restrict__ p1i, const int* __restrict__ p2i,
                                                      const float* __restrict__ gate1, const float* __restrict__ gate2,
                                                      int expert, void* __restrict__ out) {
    const int t = threadIdx.x;
    const int f32i = *dflag;
    const int c0 = t * 4;
    float bv[4];
#pragma unroll
    for (int j = 0; j < 4; j++) bv[j] = ldg(b2, b2Base + c0 + j, f32i);
    for (int r = blockIdx.x; r < CAP; r += gridDim.x) {
        int s = rowmapE[r];
        if (s < 0) continue;
        float g1 = gate1[s], g2 = gate2[s];
        float k1 = (p1i[s] >= 0) ? 1.f : 0.f, k2 = (p2i[s] >= 0) ? 1.f : 0.f;
        float denom = g1 * k1 + g2 * k2 + 1e-9f;
        float wgt = ((idx1[s] == expert) ? g1 : g2) / denom;
        float4 ev = *(const float4*)&eo32[(size_t)r * DMODEL + c0];
        size_t oi = (size_t)s * DMODEL + c0;
        if (f32i) {
            float4* po = (float4*)((float*)out + oi);
            float4 ov = *po;
            ov.x += wgt * (ev.x + bv[0]); ov.y += wgt * (ev.y + bv[1]);
            ov.z += wgt * (ev.z + bv[2]); ov.w += wgt * (ev.w + bv[3]);
            *po = ov;
        } else {
            ushort* po = (ushort*)out + oi;
            ushort4 ov = *(ushort4*)po;
            ov.x = f2bf(bf2f(ov.x) + wgt * (ev.x + bv[0]));
            ov.y = f2bf(bf2f(ov.y) + wgt * (ev.y + bv[1]));
            ov.z = f2bf(bf2f(ov.z) + wgt * (ev.z + bv[2]));
            ov.w = f2bf(bf2f(ov.w) + wgt * (ev.w + bv[3]));
            *(ushort4*)po = ov;
        }
    }
}

// ---------------- all-expert gather combine ----------------
__global__ __launch_bounds__(256) void combine_all_kernel(const float* __restrict__ eoall,
                                                          const void* __restrict__ b2,
                                                          const int* __restrict__ dflag,
                                                          const int* __restrict__ idx1, const int* __restrict__ idx2,
                                                          const int* __restrict__ p1i, const int* __restrict__ p2i,
                                                          const float* __restrict__ gate1, const float* __restrict__ gate2,
                                                          void* __restrict__ out) {
    const int s = blockIdx.x;
    const int t = threadIdx.x;
    const int c0 = t * 4;
    const int f32i = *dflag;
    const int e1 = idx1[s], e2 = idx2[s];
    const int p1 = p1i[s], p2 = p2i[s];
    const float g1 = gate1[s], g2 = gate2[s];
    const float k1 = (p1 >= 0) ? 1.f : 0.f, k2 = (p2 >= 0) ? 1.f : 0.f;
    const float denom = g1 * k1 + g2 * k2 + 1e-9f;
    const float w1 = g1 * k1 / denom, w2 = g2 * k2 / denom;
    float r0 = 0.f, r1 = 0.f, r2 = 0.f, r3 = 0.f;
    if (p1 >= 0) {
        const float4 ev = *(const float4*)&eoall[((size_t)e1 * CAP + p1) * DMODEL + c0];
        long bb = (long)e1 * DMODEL + c0;
        r0 += w1 * (ev.x + ldg(b2, bb + 0, f32i));
        r1 += w1 * (ev.y + ldg(b2, bb + 1, f32i));
        r2 += w1 * (ev.z + ldg(b2, bb + 2, f32i));
        r3 += w1 * (ev.w + ldg(b2, bb + 3, f32i));
    }
    if (p2 >= 0) {
        const float4 ev = *(const float4*)&eoall[((size_t)e2 * CAP + p2) * DMODEL + c0];
        long bb = (long)e2 * DMODEL + c0;
        r0 += w2 * (ev.x + ldg(b2, bb + 0, f32i));
        r1 += w2 * (ev.y + ldg(b2, bb + 1, f32i));
        r2 += w2 * (ev.z + ldg(b2, bb + 2, f32i));
        r3 += w2 * (ev.w + ldg(b2, bb + 3, f32i));
    }
    size_t oi = (size_t)s * DMODEL + c0;
    if (f32i) {
        float4 ov; ov.x = r0; ov.y = r1; ov.z = r2; ov.w = r3;
        *(float4*)((float*)out + oi) = ov;
    } else {
        ushort4 ov; ov.x = f2bf(r0); ov.y = f2bf(r1); ov.z = f2bf(r2); ov.w = f2bf(r3);
        *(ushort4*)((ushort*)out + oi) = ov;
    }
}

// ---------------- shared prologue ----------------
struct WsPtrs {
    int *flag, *rowmap, *idx1, *idx2, *p1i, *p2i, *c1, *c2, *base1, *base2;
    float *gate1, *gate2, *bsum, *msumB;
    ushort* xb;
};
static WsPtrs ws_ptrs(char* ws) {
    WsPtrs p;
    p.flag   = (int*)ws;
    p.rowmap = (int*)(ws + 256);
    p.gate1  = (float*)(ws + 82176);
    p.gate2  = (float*)(ws + 147712);
    p.idx1   = (int*)(ws + 213248);
    p.idx2   = (int*)(ws + 278784);
    p.p1i    = (int*)(ws + 344320);
    p.p2i    = (int*)(ws + 409856);
    p.bsum   = (float*)(ws + 475392);
    p.c1     = (int*)(ws + 606464);
    p.c2     = (int*)(ws + 608512);
    p.msumB  = (float*)(ws + 610560);
    p.base1  = (int*)(ws + 612608);
    p.base2  = (int*)(ws + 614656);
    p.xb     = (ushort*)(ws + 655360);   // 33,554,432 B
    return p;
}
static void prologue(const void* x, const void* Wg, const WsPtrs& p, void* out, hipStream_t stream,
                     bool zeroOut) {
    detect_kernel<<<dim3(1), 64, 0, stream>>>((const ushort*)x, p.flag);
    if (zeroOut) zero_kernel<<<dim3(16384), 256, 0, stream>>>(out, p.flag);
    convx_kernel<<<dim3(8192), 256, 0, stream>>>(x, p.flag, p.xb);
    gate_kernel<<<dim3(S_TOKENS / 4), 256, 0, stream>>>(x, Wg, p.flag, p.gate1, p.gate2, p.idx1, p.idx2, p.bsum);
    hist_kernel<<<dim3(NCHUNK), 256, 0, stream>>>(p.idx1, p.idx2, p.bsum, p.c1, p.c2, p.msumB, p.rowmap);
    base_kernel<<<dim3(1), 64, 0, stream>>>(p.c1, p.c2, p.msumB, p.flag, p.base1, p.base2, out);
    place_kernel<<<dim3(NCHUNK), 256, 0, stream>>>(p.idx1, p.idx2, p.base1, p.base2, p.p1i, p.p2i, p.rowmap);
}

// ---------------- expert-batched design ----------------
// EB experts per launch; fullCombine => eo32 for all 8 experts + one gather combine.
// fullCombine path: gemm2f (full-K, no atomics, no zero-init).
template<int EB>
static void run_moe_batched(const void* x, const void* Wg, const void* W1, const void* b1,
                            const void* W2, const void* b2, void* out, char* ws, hipStream_t stream,
                            bool fullCombine) {
    WsPtrs p = ws_ptrs(ws);
    char* cur = ws + 655360 + 33554432;
    ushort* h = (ushort*)cur;  cur += (size_t)EB * CAP * HFF * 2;      // EB * 20,971,520
    ushort* T = (ushort*)cur;  cur += (size_t)EB * HFF * DMODEL * 2;   // EB * 8,388,608
    float* eo = (float*)cur;   // fullCombine: 8 * CAP*D f32; else EB * CAP*D f32

    prologue(x, Wg, p, out, stream, !fullCombine);
    for (int b = 0; b < NEXP / EB; b++) {
        const int e0 = b * EB;
        float* eoS = fullCombine ? eo + (size_t)e0 * CAP * DMODEL : eo;
        transpose_conv<<<dim3(HFF / 64, DMODEL / 64, EB), 256, 0, stream>>>(
            W1, T, p.flag, (long)e0 * DMODEL * HFF, HFF, DMODEL,
            (long)DMODEL * HFF, (long)HFF * DMODEL);                     // T[z] = W1[e0+z]^T [4096][1024]
        gemm1_kernel<HFF><<<dim3(HFF / 128, CAP / 128, EB), 256, 0, stream>>>(
            p.xb, p.rowmap + e0 * CAP, T, b1, (long)e0 * HFF, p.flag, h);
        transpose_conv<<<dim3(DMODEL / 64, HFF / 64, EB), 256, 0, stream>>>(
            W2, T, p.flag, (long)e0 * HFF * DMODEL, DMODEL, HFF,
            (long)HFF * DMODEL, (long)DMODEL * HFF);                     // T[z] = W2[e0+z]^T [1024][4096]
        if (fullCombine) {
            gemm2f_kernel<HFF><<<dim3(DMODEL / 128, CAP / 128, EB), 256, 0, stream>>>(h, T, eoS);
        } else {
            zeroeo_kernel<<<dim3(4096), 256, 0, stream>>>(eoS, (size_t)EB * CAP * DMODEL);
            gemm2s_kernel<HFF, 1024><<<dim3(DMODEL / 128, CAP / 128, 4 * EB), 256, 0, stream>>>(h, T, eoS);
            for (int q = 0; q < EB; q++)
                combine_kernel<<<dim3(1280), 256, 0, stream>>>(
                    eo + (size_t)q * CAP * DMODEL, b2, (long)(e0 + q) * DMODEL, p.flag,
                    p.rowmap + (e0 + q) * CAP, p.idx1, p.p1i, p.p2i, p.gate1, p.gate2, e0 + q, out);
        }
    }
    if (fullCombine)
        combine_all_kernel<<<dim3(S_TOKENS), 256, 0, stream>>>(
            eo, b2, p.flag, p.idx1, p.idx2, p.p1i, p.p2i, p.gate1, p.gate2, out);
}

// ---------------- design A: full-H per expert (ws >= ~74.1 MB) ----------------
static void run_moe_a(const void* x, const void* Wg, const void* W1, const void* b1,
                      const void* W2, const void* b2, void* out, char* ws, hipStream_t stream) {
    WsPtrs p = ws_ptrs(ws);
    ushort* h    = (ushort*)(ws + 655360 + 33554432);            // 20,971,520
    ushort* T    = (ushort*)(ws + 655360 + 33554432 + 20971520); // 8,388,608
    float*  eo32 = (float*)(ws + 655360 + 33554432 + 20971520 + 8388608); // 10,485,760

    prologue(x, Wg, p, out, stream, true);
    for (int e = 0; e < NEXP; e++) {
        transpose_conv<<<dim3(HFF / 64, DMODEL / 64), 256, 0, stream>>>(
            W1, T, p.flag, (long)e * DMODEL * HFF, HFF, DMODEL, 0, 0);
        gemm1_kernel<HFF><<<dim3(HFF / 128, CAP / 128), 256, 0, stream>>>(
            p.xb, p.rowmap + e * CAP, T, b1, (long)e * HFF, p.flag, h);
        zeroeo_kernel<<<dim3(2048), 256, 0, stream>>>(eo32, (size_t)CAP * DMODEL);
        transpose_conv<<<dim3(DMODEL / 64, HFF / 64), 256, 0, stream>>>(
            W2, T, p.flag, (long)e * HFF * DMODEL, DMODEL, HFF, 0, 0);
        gemm2s_kernel<HFF, 512><<<dim3(DMODEL / 128, CAP / 128, HFF / 512), 256, 0, stream>>>(h, T, eo32);
        combine_kernel<<<dim3(1280), 256, 0, stream>>>(
            eo32, b2, (long)e * DMODEL, p.flag, p.rowmap + e * CAP,
            p.idx1, p.p1i, p.p2i, p.gate1, p.gate2, e, out);
    }
}

// ---------------- design B: H chunked at 2048 (ws >= ~59.4 MB) ----------------
static void run_moe_b(const void* x, const void* Wg, const void* W1, const void* b1,
                      const void* W2, const void* b2, void* out, char* ws, hipStream_t stream) {
    WsPtrs p = ws_ptrs(ws);
    const int HC = 2048;
    ushort* h    = (ushort*)(ws + 655360 + 33554432);            // 10,485,760
    ushort* T    = (ushort*)(ws + 655360 + 33554432 + 10485760); // 4,194,304
    float*  eo32 = (float*)(ws + 655360 + 33554432 + 10485760 + 4194304); // 10,485,760

    prologue(x, Wg, p, out, stream, true);
    for (int e = 0; e < NEXP; e++) {
        zeroeo_kernel<<<dim3(2048), 256, 0, stream>>>(eo32, (size_t)CAP * DMODEL);
        for (int c = 0; c < HFF / HC; c++) {
            const long hoff = (long)c * HC;
            transpose_conv<<<dim3(HC / 64, DMODEL / 64), 256, 0, stream>>>(
                W1, T, p.flag, (long)e * DMODEL * HFF + hoff, HFF, DMODEL, 0, 0);
            gemm1_kernel<HC><<<dim3(HC / 128, CAP / 128), 256, 0, stream>>>(
                p.xb, p.rowmap + e * CAP, T, b1, (long)e * HFF + hoff, p.flag, h);
            transpose_conv<<<dim3(DMODEL / 64, HC / 64), 256, 0, stream>>>(
                W2, T, p.flag, (long)e * HFF * DMODEL + hoff * DMODEL, DMODEL, HC, 0, 0);
            gemm2s_kernel<2048, 1024><<<dim3(DMODEL / 128, CAP / 128, 2), 256, 0, stream>>>(h, T, eo32);
        }
        combine_kernel<<<dim3(1280), 256, 0, stream>>>(
            eo32, b2, (long)e * DMODEL, p.flag, p.rowmap + e * CAP,
            p.idx1, p.p1i, p.p2i, p.gate1, p.gate2, e, out);
    }
}

// ---------------- launcher ----------------
extern "C" void kernel_launch(void* const* d_in, const int* in_sizes, int n_in,
                              void* d_out, int out_size, void* d_ws, size_t ws_size,
                              hipStream_t stream) {
    const void* x  = d_in[0];
    const void* Wg = d_in[1];
    const void* W1 = d_in[2];
    const void* b1 = d_in[3];
    const void* W2 = d_in[4];
    const void* b2 = d_in[5];
    char* ws = (char*)d_ws;

    // exact footprints: EB=4 full: 235,569,152 B; EB=2 full: 176,816,128 B;
    //                   EB=2 pair: 113,901,568 B; A: 74.06 MB; B: 59.38 MB
    // thresholds carry ~4 MB guard margin above the exact footprint.
    if (ws_size >= 239500000ull)      run_moe_batched<4>(x, Wg, W1, b1, W2, b2, d_out, ws, stream, true);
    else if (ws_size >= 181000000ull) run_moe_batched<2>(x, Wg, W1, b1, W2, b2, d_out, ws, stream, true);
    else if (ws_size >= 118000000ull) run_moe_batched<2>(x, Wg, W1, b1, W2, b2, d_out, ws, stream, false);
    else if (ws_size >= 78000000ull)  run_moe_a(x, Wg, W1, b1, W2, b2, d_out, ws, stream);
    else                              run_moe_b(x, Wg, W1, b1, W2, b2, d_out, ws, stream);
}

// Round 6
// 1002.101 us; speedup vs baseline: 1.8549x; 1.1393x over previous
//
#include <hip/hip_runtime.h>
#include <hip/hip_bf16.h>

// ---------------- problem constants ----------------
#define S_TOKENS 16384   // B*N
#define DMODEL   1024
#define NEXP     8
#define HFF      4096
#define CAP      2560    // int(S*1.25/E)
#define OUT_TOTAL (S_TOKENS * DMODEL + 1)
#define NCHUNK   64      // scan chunks (256 tokens each)

typedef __attribute__((ext_vector_type(8))) short bf16x8;
typedef __attribute__((ext_vector_type(4))) float f32x4;

__device__ inline float bf2f(unsigned short u) {
    union { unsigned int i; float f; } v; v.i = ((unsigned int)u) << 16; return v.f;
}
__device__ inline unsigned short f2bf(float f) {
    __hip_bfloat16 h = __float2bfloat16(f);
    return *reinterpret_cast<unsigned short*>(&h);
}
// dtype-flexible load: f32i=1 -> float*, else bf16(ushort)*
__device__ inline float ldg(const void* p, size_t i, int f32i) {
    return f32i ? ((const float*)p)[i] : bf2f(((const ushort*)p)[i]);
}
__device__ inline float gelu_tanh(float x) {
    float u = 0.7978845608028654f * (x + 0.044715f * x * x * x);
    return 0.5f * x * (1.0f + tanhf(u));
}
__device__ inline void lds16(const void* g, void* l) {
    __builtin_amdgcn_global_load_lds((const __attribute__((address_space(1))) unsigned int*)g,
                                     (__attribute__((address_space(3))) unsigned int*)l, 16, 0, 0);
}

// ---------------- dtype detection ----------------
__global__ void detect_kernel(const ushort* __restrict__ xus, int* __restrict__ flag) {
    const int lane = threadIdx.x;  // 64
    int cnt = 0;
#pragma unroll
    for (int j = 0; j < 16; j++) {
        int p = lane * 16 + j;
        int eb = (xus[2 * p] >> 7) & 0xFF;
        cnt += (eb >= 100 && eb <= 140) ? 1 : 0;
    }
#pragma unroll
    for (int off = 32; off > 0; off >>= 1) cnt += __shfl_down(cnt, off, 64);
    if (lane == 0) flag[0] = (cnt < 512) ? 1 : 0;   // 1 = f32, 0 = bf16
}

// ---------------- zero the output ----------------
__global__ __launch_bounds__(256) void zero_kernel(void* __restrict__ out, const int* __restrict__ dflag) {
    const int f32i = *dflag;
    for (size_t i = (size_t)blockIdx.x * 256 + threadIdx.x; i < OUT_TOTAL; i += (size_t)gridDim.x * 256) {
        if (f32i) ((float*)out)[i] = 0.f; else ((ushort*)out)[i] = 0;
    }
}

// ---------------- zero f32 staging ----------------
__global__ __launch_bounds__(256) void zeroeo_kernel(float* __restrict__ p, size_t n) {
    for (size_t i = (size_t)blockIdx.x * 256 + threadIdx.x; i < n; i += (size_t)gridDim.x * 256)
        p[i] = 0.f;
}

// ---------------- x -> bf16 copy ----------------
__global__ __launch_bounds__(256) void convx_kernel(const void* __restrict__ x, const int* __restrict__ dflag,
                                                    ushort* __restrict__ xb) {
    const int f32i = *dflag;
    for (size_t i = (size_t)blockIdx.x * 256 + threadIdx.x; i < (size_t)S_TOKENS * DMODEL;
         i += (size_t)gridDim.x * 256)
        xb[i] = f32i ? f2bf(((const float*)x)[i]) : ((const ushort*)x)[i];
}

// ---------------- gating ----------------
__global__ __launch_bounds__(256) void gate_kernel(const void* __restrict__ x, const void* __restrict__ Wg,
                                                   const int* __restrict__ dflag,
                                                   float* __restrict__ gate1, float* __restrict__ gate2,
                                                   int* __restrict__ idx1, int* __restrict__ idx2,
                                                   float* __restrict__ bsum) {
    __shared__ float wgs[DMODEL * NEXP];   // 32 KB
    __shared__ float gsh[4][NEXP];
    const int t = threadIdx.x;
    const int f32i = *dflag;
    for (int i = t; i < DMODEL * NEXP; i += 256) wgs[i] = ldg(Wg, i, f32i);
    __syncthreads();
    const int wave = t >> 6, lane = t & 63;
    const int s = blockIdx.x * 4 + wave;
    float acc[NEXP];
#pragma unroll
    for (int e = 0; e < NEXP; e++) acc[e] = 0.f;
#pragma unroll
    for (int i = 0; i < 16; i++) {
        int d = i * 64 + lane;
        float xv = ldg(x, (size_t)s * DMODEL + d, f32i);
        const float* w = &wgs[d * NEXP];
#pragma unroll
        for (int e = 0; e < NEXP; e++) acc[e] += xv * w[e];
    }
#pragma unroll
    for (int off = 32; off > 0; off >>= 1)
#pragma unroll
        for (int e = 0; e < NEXP; e++) acc[e] += __shfl_down(acc[e], off, 64);
    if (lane == 0) {
        float mx = acc[0];
#pragma unroll
        for (int e = 1; e < NEXP; e++) mx = fmaxf(mx, acc[e]);
        float p[NEXP], se = 0.f;
#pragma unroll
        for (int e = 0; e < NEXP; e++) { p[e] = __expf(acc[e] - mx); se += p[e]; }
        float inv = 1.0f / se;
#pragma unroll
        for (int e = 0; e < NEXP; e++) p[e] *= inv;
        int i1 = 0; float g1v = p[0];
#pragma unroll
        for (int e = 1; e < NEXP; e++) if (p[e] > g1v) { g1v = p[e]; i1 = e; }
        int i2 = -1; float g2v = -1.0f;
#pragma unroll
        for (int e = 0; e < NEXP; e++) if (e != i1 && p[e] > g2v) { g2v = p[e]; i2 = e; }
        gate1[s] = g1v; gate2[s] = g2v; idx1[s] = i1; idx2[s] = i2;
#pragma unroll
        for (int e = 0; e < NEXP; e++) gsh[wave][e] = p[e];
    }
    __syncthreads();
    if (t < NEXP) bsum[blockIdx.x * NEXP + t] = gsh[0][t] + gsh[1][t] + gsh[2][t] + gsh[3][t];
}

// ---------------- parallel capacity scan ----------------
__global__ __launch_bounds__(256) void hist_kernel(const int* __restrict__ idx1, const int* __restrict__ idx2,
                                                   const float* __restrict__ bsum,
                                                   int* __restrict__ c1, int* __restrict__ c2,
                                                   float* __restrict__ msumB, int* __restrict__ rowmap) {
    const int b = blockIdx.x, t = threadIdx.x;
    const int w = t >> 6, lane = t & 63;
    __shared__ int sc1[4][NEXP], sc2[4][NEXP];
    __shared__ float sm[256];

    for (int i = b * 256 + t; i < NEXP * CAP; i += NCHUNK * 256) rowmap[i] = -1;

    const int s = b * 256 + w * 64 + lane;
    const int id1 = idx1[s], id2 = idx2[s];
#pragma unroll
    for (int e = 0; e < NEXP; e++) {
        unsigned long long m1 = __ballot(id1 == e);
        unsigned long long m2 = __ballot(id2 == e);
        if (lane == 0) { sc1[w][e] = __popcll(m1); sc2[w][e] = __popcll(m2); }
    }
    sm[t] = bsum[b * 512 + t] + bsum[b * 512 + 256 + t];
    __syncthreads();
    if (t < NEXP) {
        c1[b * NEXP + t] = sc1[0][t] + sc1[1][t] + sc1[2][t] + sc1[3][t];
        c2[b * NEXP + t] = sc2[0][t] + sc2[1][t] + sc2[2][t] + sc2[3][t];
        float ms = 0.f;
#pragma unroll
        for (int k = 0; k < 32; k++) ms += sm[t + NEXP * k];
        msumB[b * NEXP + t] = ms;
    }
}

__global__ void base_kernel(const int* __restrict__ c1, const int* __restrict__ c2,
                            const float* __restrict__ msumB, const int* __restrict__ dflag,
                            int* __restrict__ base1, int* __restrict__ base2, void* __restrict__ out) {
    const int lane = threadIdx.x;   // 64
    float contrib = 0.f;
    if (lane < NEXP) {
        int run = 0;
        for (int b = 0; b < NCHUNK; b++) { base1[b * NEXP + lane] = run; run += c1[b * NEXP + lane]; }
        const int count1 = run;
        int run2 = count1 < CAP ? count1 : CAP;   // used1 = min(count1, C)
        for (int b = 0; b < NCHUNK; b++) { base2[b * NEXP + lane] = run2; run2 += c2[b * NEXP + lane]; }
        float ms = 0.f;
        for (int b = 0; b < NCHUNK; b++) ms += msumB[b * NEXP + lane];
        contrib = (ms / (float)S_TOKENS) * ((float)count1 / (float)S_TOKENS);
    }
#pragma unroll
    for (int off = 4; off > 0; off >>= 1) contrib += __shfl_down(contrib, off, 64);
    if (lane == 0) {
        float L = 0.08f * contrib;   // 0.01 * mean(me*ce) * E*E
        if (*dflag) ((float*)out)[(size_t)S_TOKENS * DMODEL] = L;
        else        ((ushort*)out)[(size_t)S_TOKENS * DMODEL] = f2bf(L);
    }
}

__global__ __launch_bounds__(256) void place_kernel(const int* __restrict__ idx1, const int* __restrict__ idx2,
                                                    const int* __restrict__ base1, const int* __restrict__ base2,
                                                    int* __restrict__ p1i, int* __restrict__ p2i,
                                                    int* __restrict__ rowmap) {
    const int b = blockIdx.x, t = threadIdx.x;
    const int w = t >> 6, lane = t & 63;
    const unsigned long long below = (1ull << lane) - 1ull;
    __shared__ int wc1[4][NEXP], wc2[4][NEXP];
    const int s = b * 256 + w * 64 + lane;
    const int id1 = idx1[s], id2 = idx2[s];
    int r1 = 0, r2 = 0;
#pragma unroll
    for (int e = 0; e < NEXP; e++) {
        unsigned long long m1 = __ballot(id1 == e);
        if (id1 == e) r1 = __popcll(m1 & below);
        unsigned long long m2 = __ballot(id2 == e);
        if (id2 == e) r2 = __popcll(m2 & below);
        if (lane == 0) { wc1[w][e] = __popcll(m1); wc2[w][e] = __popcll(m2); }
    }
    __syncthreads();
    int off1 = 0, off2 = 0;
#pragma unroll
    for (int ww = 0; ww < 3; ww++) {
        if (ww < w) { off1 += wc1[ww][id1]; off2 += wc2[ww][id2]; }
    }
    const int pos1 = base1[b * NEXP + id1] + off1 + r1;
    if (pos1 < CAP) { p1i[s] = pos1; rowmap[id1 * CAP + pos1] = s; } else p1i[s] = -1;
    const int pos2 = base2[b * NEXP + id2] + off2 + r2;
    if (pos2 < CAP) { p2i[s] = pos2; rowmap[id2 * CAP + pos2] = s; } else p2i[s] = -1;
}

// ---------------- transpose + convert (expert-batched over blockIdx.z) ----------------
__global__ __launch_bounds__(256) void transpose_conv(const void* __restrict__ src, ushort* __restrict__ dst,
                                                      const int* __restrict__ dflag,
                                                      long srcBase, int srcStride, int dstStride,
                                                      long srcExpStride, long dstExpStride) {
    __shared__ ushort tile[64][68];
    const int f32i = *dflag;
    srcBase += (long)blockIdx.z * srcExpStride;
    dst     += (size_t)blockIdx.z * dstExpStride;
    const int c0 = blockIdx.x * 64, r0 = blockIdx.y * 64;
    const int tx = threadIdx.x & 15, ty = threadIdx.x >> 4;
#pragma unroll
    for (int k = 0; k < 4; k++) {
        int row = ty + 16 * k;
        size_t b = (size_t)srcBase + (size_t)(r0 + row) * srcStride + c0 + tx * 4;
#pragma unroll
        for (int j = 0; j < 4; j++) tile[row][tx * 4 + j] = f2bf(ldg(src, b + j, f32i));
    }
    __syncthreads();
#pragma unroll
    for (int k = 0; k < 4; k++) {
        int orow = ty + 16 * k;
        ushort4 v;
        v.x = tile[tx * 4 + 0][orow];
        v.y = tile[tx * 4 + 1][orow];
        v.z = tile[tx * 4 + 2][orow];
        v.w = tile[tx * 4 + 3][orow];
        *(ushort4*)(dst + (size_t)(c0 + orow) * dstStride + r0 + tx * 4) = v;
    }
}

// ---------------- GEMM1 (1D grid, XCD-aware decode; 4-wave 128x128) ----------------
// grid = (NC/128)*(CAP/128)*EB blocks (multiple of 8). Same-XCD consecutive blocks share the A-strip.
template<int NC, int EB>
__global__ __launch_bounds__(256) void gemm1_kernel(const ushort* __restrict__ xb,
                                                    const int* __restrict__ rowmapBase,
                                                    const ushort* __restrict__ T,
                                                    const void* __restrict__ b1, long biasBase,
                                                    const int* __restrict__ dflag,
                                                    ushort* __restrict__ hout) {
    __shared__ ushort lA[128 * 32];
    __shared__ ushort lB[128 * 32];
    constexpr int TN = NC / 128, TM = CAP / 128;
    constexpr int TOTAL = TN * TM * EB, CHUNK = TOTAL / 8;
    const int l = blockIdx.x;
    const int ord = (l & 7) * CHUNK + (l >> 3);
    const int z = ord / (TN * TM);
    const int rem = ord - z * (TN * TM);
    const int m0 = (rem / TN) * 128, n0 = (rem % TN) * 128;
    const int* rowmapE = rowmapBase + z * CAP;
    T    += (size_t)z * NC * DMODEL;
    hout += (size_t)z * CAP * NC;
    biasBase += (long)z * HFF;
    const int t = threadIdx.x;
    const int w = t >> 6, lane = t & 63;
    const int wr = w >> 1, wc = w & 1;
    const int l15 = lane & 15, quad = lane >> 4;
    const int swz = (lane >> 3) & 3;                 // staging source swizzle
    const int q2 = quad ^ ((l15 >> 1) & 3);          // read-side swizzle

    int arow[2];
#pragma unroll
    for (int it = 0; it < 2; it++) {
        int r = (it * 2048 + w * 512 + lane * 8) >> 5;
        int rm = rowmapE[m0 + r];
        arow[it] = rm < 0 ? 0 : rm;
    }

    f32x4 acc[4][4];
#pragma unroll
    for (int i = 0; i < 4; i++)
#pragma unroll
        for (int j = 0; j < 4; j++) acc[i][j] = (f32x4){0.f, 0.f, 0.f, 0.f};

    for (int k0 = 0; k0 < DMODEL; k0 += 32) {
        __syncthreads();
#pragma unroll
        for (int it = 0; it < 2; it++) {
            int f = it * 2048 + w * 512 + lane * 8;
            int r = f >> 5, kk = (f & 31) ^ (swz << 3);
            lds16(xb + (size_t)arow[it] * DMODEL + k0 + kk, &lA[it * 2048 + w * 512]);
            lds16(T + (size_t)(n0 + r) * DMODEL + k0 + kk, &lB[it * 2048 + w * 512]);
        }
        __syncthreads();
        bf16x8 af[4], bfr[4];
#pragma unroll
        for (int i = 0; i < 4; i++) af[i] = *(const bf16x8*)&lA[(wr * 64 + i * 16 + l15) * 32 + q2 * 8];
#pragma unroll
        for (int j = 0; j < 4; j++) bfr[j] = *(const bf16x8*)&lB[(wc * 64 + j * 16 + l15) * 32 + q2 * 8];
#pragma unroll
        for (int i = 0; i < 4; i++)
#pragma unroll
            for (int j = 0; j < 4; j++)
                acc[i][j] = __builtin_amdgcn_mfma_f32_16x16x32_bf16(af[i], bfr[j], acc[i][j], 0, 0, 0);
    }
    const int f32i = *dflag;
    float bv[4];
#pragma unroll
    for (int j = 0; j < 4; j++) bv[j] = ldg(b1, biasBase + n0 + wc * 64 + j * 16 + l15, f32i);
#pragma unroll
    for (int i = 0; i < 4; i++) {
        int row0 = m0 + wr * 64 + i * 16 + quad * 4;
#pragma unroll
        for (int j = 0; j < 4; j++) {
            int col = n0 + wc * 64 + j * 16 + l15;
#pragma unroll
            for (int r = 0; r < 4; r++)
                hout[(size_t)(row0 + r) * NC + col] = f2bf(gelu_tanh(acc[i][j][r] + bv[j]));
        }
    }
}

// ---------------- GEMM2 full-K, 8-wave (512 thr), 1D grid XCD-aware, output-stationary ----------------
// eo32[ze][row][col] = h[ze] @ T2[ze]^T ; plain f32 stores, no zero-init.
// Per-wave subtile 64m x 32n (wave grid 2x4). Staging: each thread 2x lds16 (16B).
// Swizzle involution: phys[r][c] = global[r][c ^ (((r>>1)&3)<<3)], read col q2*8.
template<int KC, int EB>
__global__ __launch_bounds__(512) void gemm2f8_kernel(const ushort* __restrict__ h,
                                                      const ushort* __restrict__ T2,
                                                      float* __restrict__ eo32) {
    __shared__ ushort lA[128 * 32];
    __shared__ ushort lB[128 * 32];
    constexpr int TN = DMODEL / 128, TM = CAP / 128;
    constexpr int TOTAL = TN * TM * EB, CHUNK = TOTAL / 8;
    const int l = blockIdx.x;
    const int ord = (l & 7) * CHUNK + (l >> 3);
    const int ze = ord / (TN * TM);
    const int rem = ord - ze * (TN * TM);
    const int m0 = (rem / TN) * 128, n0 = (rem % TN) * 128;
    h    += (size_t)ze * CAP * KC;
    T2   += (size_t)ze * DMODEL * KC;
    eo32 += (size_t)ze * CAP * DMODEL;
    const int t = threadIdx.x;
    const int w = t >> 6, lane = t & 63;
    const int wr = w >> 2, wc = w & 3;               // 2x4 wave grid
    const int l15 = lane & 15, quad = lane >> 4;
    const int q2 = quad ^ ((l15 >> 1) & 3);
    const int sr = t >> 2;                           // staging row 0..127
    const int kk = ((t & 3) * 8) ^ (((t >> 3) & 3) << 3);

    f32x4 acc[4][2];
#pragma unroll
    for (int i = 0; i < 4; i++)
#pragma unroll
        for (int j = 0; j < 2; j++) acc[i][j] = (f32x4){0.f, 0.f, 0.f, 0.f};

    for (int k0 = 0; k0 < KC; k0 += 32) {
        __syncthreads();
        lds16(h  + (size_t)(m0 + sr) * KC + k0 + kk, &lA[t * 8]);
        lds16(T2 + (size_t)(n0 + sr) * KC + k0 + kk, &lB[t * 8]);
        __syncthreads();
        bf16x8 af[4], bfr[2];
#pragma unroll
        for (int i = 0; i < 4; i++) af[i] = *(const bf16x8*)&lA[(wr * 64 + i * 16 + l15) * 32 + q2 * 8];
#pragma unroll
        for (int j = 0; j < 2; j++) bfr[j] = *(const bf16x8*)&lB[(wc * 32 + j * 16 + l15) * 32 + q2 * 8];
#pragma unroll
        for (int i = 0; i < 4; i++)
#pragma unroll
            for (int j = 0; j < 2; j++)
                acc[i][j] = __builtin_amdgcn_mfma_f32_16x16x32_bf16(af[i], bfr[j], acc[i][j], 0, 0, 0);
    }
#pragma unroll
    for (int i = 0; i < 4; i++) {
#pragma unroll
        for (int r = 0; r < 4; r++) {
            int row = m0 + wr * 64 + i * 16 + quad * 4 + r;
#pragma unroll
            for (int j = 0; j < 2; j++) {
                int col = n0 + wc * 32 + j * 16 + l15;
                eo32[(size_t)row * DMODEL + col] = acc[i][j][r];
            }
        }
    }
}

// ---------------- GEMM2 split-K (legacy tiers): eo32 += h @ T2^T (f32 atomics) ----------------
template<int KC, int KB>
__global__ __launch_bounds__(256) void gemm2s_kernel(const ushort* __restrict__ h,
                                                     const ushort* __restrict__ T2,
                                                     float* __restrict__ eo32) {
    __shared__ ushort lA[128 * 32];
    __shared__ ushort lB[128 * 32];
    constexpr int KSPLIT = KC / KB;
    const int zz = blockIdx.z;
    const int ze = zz / KSPLIT, zk = zz - ze * KSPLIT;
    h    += (size_t)ze * CAP * KC;
    T2   += (size_t)ze * DMODEL * KC;
    eo32 += (size_t)ze * CAP * DMODEL;
    const int t = threadIdx.x;
    const int w = t >> 6, lane = t & 63;
    const int n0 = blockIdx.x * 128, m0 = blockIdx.y * 128;
    const int kbeg = zk * KB;
    const int wr = w >> 1, wc = w & 1;
    const int l15 = lane & 15, quad = lane >> 4;
    const int swz = (lane >> 3) & 3;
    const int q2 = quad ^ ((l15 >> 1) & 3);

    f32x4 acc[4][4];
#pragma unroll
    for (int i = 0; i < 4; i++)
#pragma unroll
        for (int j = 0; j < 4; j++) acc[i][j] = (f32x4){0.f, 0.f, 0.f, 0.f};

    for (int k0 = kbeg; k0 < kbeg + KB; k0 += 32) {
        __syncthreads();
#pragma unroll
        for (int it = 0; it < 2; it++) {
            int f = it * 2048 + w * 512 + lane * 8;
            int r = f >> 5, kk = (f & 31) ^ (swz << 3);
            lds16(h  + (size_t)(m0 + r) * KC + k0 + kk, &lA[it * 2048 + w * 512]);
            lds16(T2 + (size_t)(n0 + r) * KC + k0 + kk, &lB[it * 2048 + w * 512]);
        }
        __syncthreads();
        bf16x8 af[4], bfr[4];
#pragma unroll
        for (int i = 0; i < 4; i++) af[i] = *(const bf16x8*)&lA[(wr * 64 + i * 16 + l15) * 32 + q2 * 8];
#pragma unroll
        for (int j = 0; j < 4; j++) bfr[j] = *(const bf16x8*)&lB[(wc * 64 + j * 16 + l15) * 32 + q2 * 8];
#pragma unroll
        for (int i = 0; i < 4; i++)
#pragma unroll
            for (int j = 0; j < 4; j++)
                acc[i][j] = __builtin_amdgcn_mfma_f32_16x16x32_bf16(af[i], bfr[j], acc[i][j], 0, 0, 0);
    }
#pragma unroll
    for (int i = 0; i < 4; i++) {
#pragma unroll
        for (int r = 0; r < 4; r++) {
            int row = m0 + wr * 64 + i * 16 + quad * 4 + r;
#pragma unroll
            for (int j = 0; j < 4; j++) {
                int col = n0 + wc * 64 + j * 16 + l15;
                atomicAdd(&eo32[(size_t)row * DMODEL + col], acc[i][j][r]);
            }
        }
    }
}

// ---------------- per-expert combine (scatter, sequential launches) ----------------
__global__ __launch_bounds__(256) void combine_kernel(const float* __restrict__ eo32, const void* __restrict__ b2,
                                                      long b2Base, const int* __restrict__ dflag,
                                                      const int* __restrict__ rowmapE, const int* __restrict__ idx1,
                                                      const int* __restrict__ p1i, const int* __restrict__ p2i,
                                                      const float* __restrict__ gate1, const float* __restrict__ gate2,
                                                      int expert, void* __restrict__ out) {
    const int t = threadIdx.x;
    const int f32i = *dflag;
    const int c0 = t * 4;
    float bv[4];
#pragma unroll
    for (int j = 0; j < 4; j++) bv[j] = ldg(b2, b2Base + c0 + j, f32i);
    for (int r = blockIdx.x; r < CAP; r += gridDim.x) {
        int s = rowmapE[r];
        if (s < 0) continue;
        float g1 = gate1[s], g2 = gate2[s];
        float k1 = (p1i[s] >= 0) ? 1.f : 0.f, k2 = (p2i[s] >= 0) ? 1.f : 0.f;
        float denom = g1 * k1 + g2 * k2 + 1e-9f;
        float wgt = ((idx1[s] == expert) ? g1 : g2) / denom;
        float4 ev = *(const float4*)&eo32[(size_t)r * DMODEL + c0];
        size_t oi = (size_t)s * DMODEL + c0;
        if (f32i) {
            float4* po = (float4*)((float*)out + oi);
            float4 ov = *po;
            ov.x += wgt * (ev.x + bv[0]); ov.y += wgt * (ev.y + bv[1]);
            ov.z += wgt * (ev.z + bv[2]); ov.w += wgt * (ev.w + bv[3]);
            *po = ov;
        } else {
            ushort* po = (ushort*)out + oi;
            ushort4 ov = *(ushort4*)po;
            ov.x = f2bf(bf2f(ov.x) + wgt * (ev.x + bv[0]));
            ov.y = f2bf(bf2f(ov.y) + wgt * (ev.y + bv[1]));
            ov.z = f2bf(bf2f(ov.z) + wgt * (ev.z + bv[2]));
            ov.w = f2bf(bf2f(ov.w) + wgt * (ev.w + bv[3]));
            *(ushort4*)po = ov;
        }
    }
}

// ---------------- all-expert gather combine ----------------
__global__ __launch_bounds__(256) void combine_all_kernel(const float* __restrict__ eoall,
                                                          const void* __restrict__ b2,
                                                          const int* __restrict__ dflag,
                                                          const int* __restrict__ idx1, const int* __restrict__ idx2,
                                                          const int* __restrict__ p1i, const int* __restrict__ p2i,
                                                          const float* __restrict__ gate1, const float* __restrict__ gate2,
                                                          void* __restrict__ out) {
    const int s = blockIdx.x;
    const int t = threadIdx.x;
    const int c0 = t * 4;
    const int f32i = *dflag;
    const int e1 = idx1[s], e2 = idx2[s];
    const int p1 = p1i[s], p2 = p2i[s];
    const float g1 = gate1[s], g2 = gate2[s];
    const float k1 = (p1 >= 0) ? 1.f : 0.f, k2 = (p2 >= 0) ? 1.f : 0.f;
    const float denom = g1 * k1 + g2 * k2 + 1e-9f;
    const float w1 = g1 * k1 / denom, w2 = g2 * k2 / denom;
    float r0 = 0.f, r1 = 0.f, r2 = 0.f, r3 = 0.f;
    if (p1 >= 0) {
        const float4 ev = *(const float4*)&eoall[((size_t)e1 * CAP + p1) * DMODEL + c0];
        long bb = (long)e1 * DMODEL + c0;
        r0 += w1 * (ev.x + ldg(b2, bb + 0, f32i));
        r1 += w1 * (ev.y + ldg(b2, bb + 1, f32i));
        r2 += w1 * (ev.z + ldg(b2, bb + 2, f32i));
        r3 += w1 * (ev.w + ldg(b2, bb + 3, f32i));
    }
    if (p2 >= 0) {
        const float4 ev = *(const float4*)&eoall[((size_t)e2 * CAP + p2) * DMODEL + c0];
        long bb = (long)e2 * DMODEL + c0;
        r0 += w2 * (ev.x + ldg(b2, bb + 0, f32i));
        r1 += w2 * (ev.y + ldg(b2, bb + 1, f32i));
        r2 += w2 * (ev.z + ldg(b2, bb + 2, f32i));
        r3 += w2 * (ev.w + ldg(b2, bb + 3, f32i));
    }
    size_t oi = (size_t)s * DMODEL + c0;
    if (f32i) {
        float4 ov; ov.x = r0; ov.y = r1; ov.z = r2; ov.w = r3;
        *(float4*)((float*)out + oi) = ov;
    } else {
        ushort4 ov; ov.x = f2bf(r0); ov.y = f2bf(r1); ov.z = f2bf(r2); ov.w = f2bf(r3);
        *(ushort4*)((ushort*)out + oi) = ov;
    }
}

// ---------------- shared prologue ----------------
struct WsPtrs {
    int *flag, *rowmap, *idx1, *idx2, *p1i, *p2i, *c1, *c2, *base1, *base2;
    float *gate1, *gate2, *bsum, *msumB;
    ushort* xb;
};
static WsPtrs ws_ptrs(char* ws) {
    WsPtrs p;
    p.flag   = (int*)ws;
    p.rowmap = (int*)(ws + 256);
    p.gate1  = (float*)(ws + 82176);
    p.gate2  = (float*)(ws + 147712);
    p.idx1   = (int*)(ws + 213248);
    p.idx2   = (int*)(ws + 278784);
    p.p1i    = (int*)(ws + 344320);
    p.p2i    = (int*)(ws + 409856);
    p.bsum   = (float*)(ws + 475392);
    p.c1     = (int*)(ws + 606464);
    p.c2     = (int*)(ws + 608512);
    p.msumB  = (float*)(ws + 610560);
    p.base1  = (int*)(ws + 612608);
    p.base2  = (int*)(ws + 614656);
    p.xb     = (ushort*)(ws + 655360);   // 33,554,432 B
    return p;
}
static void prologue(const void* x, const void* Wg, const WsPtrs& p, void* out, hipStream_t stream,
                     bool zeroOut) {
    detect_kernel<<<dim3(1), 64, 0, stream>>>((const ushort*)x, p.flag);
    if (zeroOut) zero_kernel<<<dim3(16384), 256, 0, stream>>>(out, p.flag);
    convx_kernel<<<dim3(8192), 256, 0, stream>>>(x, p.flag, p.xb);
    gate_kernel<<<dim3(S_TOKENS / 4), 256, 0, stream>>>(x, Wg, p.flag, p.gate1, p.gate2, p.idx1, p.idx2, p.bsum);
    hist_kernel<<<dim3(NCHUNK), 256, 0, stream>>>(p.idx1, p.idx2, p.bsum, p.c1, p.c2, p.msumB, p.rowmap);
    base_kernel<<<dim3(1), 64, 0, stream>>>(p.c1, p.c2, p.msumB, p.flag, p.base1, p.base2, out);
    place_kernel<<<dim3(NCHUNK), 256, 0, stream>>>(p.idx1, p.idx2, p.base1, p.base2, p.p1i, p.p2i, p.rowmap);
}

// ---------------- expert-batched design ----------------
// EB experts per launch; fullCombine => eo32 for all 8 experts + one gather combine.
template<int EB>
static void run_moe_batched(const void* x, const void* Wg, const void* W1, const void* b1,
                            const void* W2, const void* b2, void* out, char* ws, hipStream_t stream,
                            bool fullCombine) {
    WsPtrs p = ws_ptrs(ws);
    char* cur = ws + 655360 + 33554432;
    ushort* h = (ushort*)cur;  cur += (size_t)EB * CAP * HFF * 2;      // EB * 20,971,520
    ushort* T = (ushort*)cur;  cur += (size_t)EB * HFF * DMODEL * 2;   // EB * 8,388,608
    float* eo = (float*)cur;   // fullCombine: 8 * CAP*D f32; else EB * CAP*D f32

    prologue(x, Wg, p, out, stream, !fullCombine);
    for (int b = 0; b < NEXP / EB; b++) {
        const int e0 = b * EB;
        float* eoS = fullCombine ? eo + (size_t)e0 * CAP * DMODEL : eo;
        transpose_conv<<<dim3(HFF / 64, DMODEL / 64, EB), 256, 0, stream>>>(
            W1, T, p.flag, (long)e0 * DMODEL * HFF, HFF, DMODEL,
            (long)DMODEL * HFF, (long)HFF * DMODEL);                     // T[z] = W1[e0+z]^T [4096][1024]
        gemm1_kernel<HFF, EB><<<dim3((HFF / 128) * (CAP / 128) * EB), 256, 0, stream>>>(
            p.xb, p.rowmap + e0 * CAP, T, b1, (long)e0 * HFF, p.flag, h);
        transpose_conv<<<dim3(DMODEL / 64, HFF / 64, EB), 256, 0, stream>>>(
            W2, T, p.flag, (long)e0 * HFF * DMODEL, DMODEL, HFF,
            (long)HFF * DMODEL, (long)DMODEL * HFF);                     // T[z] = W2[e0+z]^T [1024][4096]
        if (fullCombine) {
            gemm2f8_kernel<HFF, EB><<<dim3((DMODEL / 128) * (CAP / 128) * EB), 512, 0, stream>>>(h, T, eoS);
        } else {
            zeroeo_kernel<<<dim3(4096), 256, 0, stream>>>(eoS, (size_t)EB * CAP * DMODEL);
            gemm2s_kernel<HFF, 1024><<<dim3(DMODEL / 128, CAP / 128, 4 * EB), 256, 0, stream>>>(h, T, eoS);
            for (int q = 0; q < EB; q++)
                combine_kernel<<<dim3(1280), 256, 0, stream>>>(
                    eo + (size_t)q * CAP * DMODEL, b2, (long)(e0 + q) * DMODEL, p.flag,
                    p.rowmap + (e0 + q) * CAP, p.idx1, p.p1i, p.p2i, p.gate1, p.gate2, e0 + q, out);
        }
    }
    if (fullCombine)
        combine_all_kernel<<<dim3(S_TOKENS), 256, 0, stream>>>(
            eo, b2, p.flag, p.idx1, p.idx2, p.p1i, p.p2i, p.gate1, p.gate2, out);
}

// ---------------- design A: full-H per expert (ws >= ~78 MB) ----------------
static void run_moe_a(const void* x, const void* Wg, const void* W1, const void* b1,
                      const void* W2, const void* b2, void* out, char* ws, hipStream_t stream) {
    WsPtrs p = ws_ptrs(ws);
    ushort* h    = (ushort*)(ws + 655360 + 33554432);            // 20,971,520
    ushort* T    = (ushort*)(ws + 655360 + 33554432 + 20971520); // 8,388,608
    float*  eo32 = (float*)(ws + 655360 + 33554432 + 20971520 + 8388608); // 10,485,760

    prologue(x, Wg, p, out, stream, true);
    for (int e = 0; e < NEXP; e++) {
        transpose_conv<<<dim3(HFF / 64, DMODEL / 64), 256, 0, stream>>>(
            W1, T, p.flag, (long)e * DMODEL * HFF, HFF, DMODEL, 0, 0);
        gemm1_kernel<HFF, 1><<<dim3((HFF / 128) * (CAP / 128)), 256, 0, stream>>>(
            p.xb, p.rowmap + e * CAP, T, b1, (long)e * HFF, p.flag, h);
        zeroeo_kernel<<<dim3(2048), 256, 0, stream>>>(eo32, (size_t)CAP * DMODEL);
        transpose_conv<<<dim3(DMODEL / 64, HFF / 64), 256, 0, stream>>>(
            W2, T, p.flag, (long)e * HFF * DMODEL, DMODEL, HFF, 0, 0);
        gemm2s_kernel<HFF, 512><<<dim3(DMODEL / 128, CAP / 128, HFF / 512), 256, 0, stream>>>(h, T, eo32);
        combine_kernel<<<dim3(1280), 256, 0, stream>>>(
            eo32, b2, (long)e * DMODEL, p.flag, p.rowmap + e * CAP,
            p.idx1, p.p1i, p.p2i, p.gate1, p.gate2, e, out);
    }
}

// ---------------- design B: H chunked at 2048 (fallback) ----------------
static void run_moe_b(const void* x, const void* Wg, const void* W1, const void* b1,
                      const void* W2, const void* b2, void* out, char* ws, hipStream_t stream) {
    WsPtrs p = ws_ptrs(ws);
    const int HC = 2048;
    ushort* h    = (ushort*)(ws + 655360 + 33554432);            // 10,485,760
    ushort* T    = (ushort*)(ws + 655360 + 33554432 + 10485760); // 4,194,304
    float*  eo32 = (float*)(ws + 655360 + 33554432 + 10485760 + 4194304); // 10,485,760

    prologue(x, Wg, p, out, stream, true);
    for (int e = 0; e < NEXP; e++) {
        zeroeo_kernel<<<dim3(2048), 256, 0, stream>>>(eo32, (size_t)CAP * DMODEL);
        for (int c = 0; c < HFF / HC; c++) {
            const long hoff = (long)c * HC;
            transpose_conv<<<dim3(HC / 64, DMODEL / 64), 256, 0, stream>>>(
                W1, T, p.flag, (long)e * DMODEL * HFF + hoff, HFF, DMODEL, 0, 0);
            gemm1_kernel<2048, 1><<<dim3((2048 / 128) * (CAP / 128)), 256, 0, stream>>>(
                p.xb, p.rowmap + e * CAP, T, b1, (long)e * HFF + hoff, p.flag, h);
            transpose_conv<<<dim3(DMODEL / 64, HC / 64), 256, 0, stream>>>(
                W2, T, p.flag, (long)e * HFF * DMODEL + hoff * DMODEL, DMODEL, HC, 0, 0);
            gemm2s_kernel<2048, 1024><<<dim3(DMODEL / 128, CAP / 128, 2), 256, 0, stream>>>(h, T, eo32);
        }
        combine_kernel<<<dim3(1280), 256, 0, stream>>>(
            eo32, b2, (long)e * DMODEL, p.flag, p.rowmap + e * CAP,
            p.idx1, p.p1i, p.p2i, p.gate1, p.gate2, e, out);
    }
}

// ---------------- launcher ----------------
extern "C" void kernel_launch(void* const* d_in, const int* in_sizes, int n_in,
                              void* d_out, int out_size, void* d_ws, size_t ws_size,
                              hipStream_t stream) {
    const void* x  = d_in[0];
    const void* Wg = d_in[1];
    const void* W1 = d_in[2];
    const void* b1 = d_in[3];
    const void* W2 = d_in[4];
    const void* b2 = d_in[5];
    char* ws = (char*)d_ws;

    // exact footprints: EB=4 full: 235,569,152 B; EB=2 full: 176,816,128 B;
    //                   EB=2 pair: 113,901,568 B; A: 74.06 MB; B: 59.38 MB
    // thresholds carry ~4 MB guard margin above the exact footprint.
    if (ws_size >= 239500000ull)      run_moe_batched<4>(x, Wg, W1, b1, W2, b2, d_out, ws, stream, true);
    else if (ws_size >= 181000000ull) run_moe_batched<2>(x, Wg, W1, b1, W2, b2, d_out, ws, stream, true);
    else if (ws_size >= 118000000ull) run_moe_batched<2>(x, Wg, W1, b1, W2, b2, d_out, ws, stream, false);
    else if (ws_size >= 78000000ull)  run_moe_a(x, Wg, W1, b1, W2, b2, d_out, ws, stream);
    else                              run_moe_b(x, Wg, W1, b1, W2, b2, d_out, ws, stream);
}